// Round 8
// baseline (1118.562 us; speedup 1.0000x reference)
//
#include <hip/hip_runtime.h>

// FlashAttentionWrapper: B=2, S=2048, D=2048, NH=32, HD=64, NKV=8, NREP=4,
// causal, RoPE theta=1e4. Input dtype (bf16/f32) self-detected per block.
// New-path workspace (64MB+1KB+512KB):
//   [1KB pad][kvbuf 4096x1024 8MB][abuf 4096x2048 16MB]
//   [hbuf 16MB][wqb 8MB][wkvb 4MB][wob 8MB][vtbuf 2x512x2048 4MB]
//   [ropetab 2048x32 float2 512KB]
// wqb+wkvb are CONTIGUOUS => one [3072,2048] QKV weight matrix (fused GEMM).
// Q-projection result lives in d_out (dead before O-proj overwrites it).
// Fallback path (ws too small): original direct-load kernels, 24MB+1KB.
//
// Round-5 lesson: hand-written v_cvt_pk_bf16_f32 asm mis-packed (absmax 3.6);
// f2bf uses the compiler's native __bf16 cast.
// Round-8: attn occupancy 2->3 waves/SIMD (launch_bounds(256,3), grid 1024
// heavy-first); XCD-chunked swizzle on GEMMs; rope table folded into cvt_all.

#define S_LEN 2048
#define D_MODEL 2048
#define NHEAD 32
#define HEAD_DIM 64
#define NKVH 8
#define M_ROWS 4096   // B*S
#define KVW (NKVH * HEAD_DIM)   // 512

typedef __attribute__((ext_vector_type(4))) float f32x4;
typedef __attribute__((ext_vector_type(8))) short bf16x8;

#define MFMA16(a, b, c) __builtin_amdgcn_mfma_f32_16x16x32_bf16((a), (b), (c), 0, 0, 0)

// async global->LDS, 16B per lane; LDS dest is wave-uniform base + lane*16
#define GLOAD_LDS16(g, l)                                                     \
    __builtin_amdgcn_global_load_lds(                                         \
        (const __attribute__((address_space(1))) void*)(g),                   \
        (__attribute__((address_space(3))) void*)(l), 16, 0, 0)

// f32 -> bf16 RNE via native cast (compiler emits the HW convert).
static __device__ __forceinline__ unsigned short f2bf(float f) {
    union { __bf16 b; unsigned short u; } v;
    v.b = (__bf16)f;
    return v.u;
}

static __device__ __forceinline__ float fexp2(float x) {
#if __has_builtin(__builtin_amdgcn_exp2f)
    return __builtin_amdgcn_exp2f(x);
#else
    return exp2f(x);
#endif
}

// XCD-chunked swizzle of a 2D grid (requires gridDim.x*gridDim.y % 8 == 0).
// Consecutive work ids (same blockIdx.y => same W panel) land on one XCD.
static __device__ __forceinline__ void xcd_swz(int& bx, int& by) {
    const int gx = gridDim.x;
    const int nwg = gx * gridDim.y;
    int lin = blockIdx.y * gx + blockIdx.x;
    lin = (lin & 7) * (nwg >> 3) + (lin >> 3);
    bx = lin % gx;
    by = lin / gx;
}

// ---------------------------------------------------------------------------
// Per-block dtype self-detection: f32 data read as uint16 shows impossible
// bf16 exponents at even indices. Called uniformly by all 256 threads.
// ---------------------------------------------------------------------------
static __device__ bool detect_f32_block(const unsigned short* __restrict__ h) {
    __shared__ int dcnt;
    if (threadIdx.x == 0) dcnt = 0;
    __syncthreads();
    const unsigned short v = h[2 * (threadIdx.x & 255)];
    const int e = (v >> 7) & 0xFF;
    if (threadIdx.x < 256 && e >= 0x8D) atomicAdd(&dcnt, 1);
    __syncthreads();
    return dcnt >= 8;
}

static __device__ __forceinline__ bf16x8 load_frag(bool f32p, const void* p, size_t off) {
    if (f32p) {
        const float* fp = (const float*)p + off;
        f32x4 x = *reinterpret_cast<const f32x4*>(fp);
        f32x4 y = *reinterpret_cast<const f32x4*>(fp + 4);
        bf16x8 r;
        r[0] = (short)f2bf(x[0]); r[1] = (short)f2bf(x[1]);
        r[2] = (short)f2bf(x[2]); r[3] = (short)f2bf(x[3]);
        r[4] = (short)f2bf(y[0]); r[5] = (short)f2bf(y[1]);
        r[6] = (short)f2bf(y[2]); r[7] = (short)f2bf(y[3]);
        return r;
    }
    return *reinterpret_cast<const bf16x8*>((const unsigned short*)p + off);
}

// ---------------------------------------------------------------------------
// Fused one-time f32->bf16 conversion (or bf16 copy) of all 5 operands,
// plus the RoPE cos/sin table (tab[s*32+dd] = cos/sin of s*10000^(-dd/32)).
// ---------------------------------------------------------------------------
__global__ __launch_bounds__(256) void cvt_all(const void* __restrict__ h,
                                               const void* __restrict__ wq,
                                               const void* __restrict__ wk,
                                               const void* __restrict__ wv,
                                               const void* __restrict__ wo,
                                               unsigned short* __restrict__ hbuf,
                                               unsigned short* __restrict__ wqb,
                                               unsigned short* __restrict__ wkvb,
                                               unsigned short* __restrict__ wob,
                                               float2* __restrict__ ropetab) {
    const bool f32p = detect_f32_block((const unsigned short*)h);
    const int e0 = 1048576;            // hidden 4096x2048
    const int e1 = e0 + 524288;        // Wq 2048x2048
    const int e2 = e1 + 131072;        // Wk 512x2048
    const int e3 = e2 + 131072;        // Wv 512x2048
    const int e4 = e3 + 524288;        // Wo 2048x2048
    const int e5 = e4 + 8192;          // rope table 2048x32 (8 entries/unit)
    int i = blockIdx.x * 256 + threadIdx.x;
    const int stride = gridDim.x * 256;
    for (; i < e5; i += stride) {
        if (i >= e4) {
            const int base = (i - e4) * 8;
#pragma unroll
            for (int j = 0; j < 8; ++j) {
                const int idx = base + j;
                const int s = idx >> 5, dd = idx & 31;
                const float inv = exp2f(-(float)dd * 0.4152410118609203f);
                const float th = (float)s * inv;
                float sn, cs;
                sincosf(th, &sn, &cs);
                ropetab[idx] = make_float2(cs, sn);
            }
            continue;
        }
        const void* s;
        unsigned short* d;
        size_t off;
        if (i < e0)      { s = h;  d = hbuf; off = (size_t)i; }
        else if (i < e1) { s = wq; d = wqb;  off = (size_t)(i - e0); }
        else if (i < e2) { s = wk; d = wkvb; off = (size_t)(i - e1); }
        else if (i < e3) { s = wv; d = wkvb + (size_t)512 * 2048; off = (size_t)(i - e2); }
        else             { s = wo; d = wob;  off = (size_t)(i - e3); }
        bf16x8 v = load_frag(f32p, s, off * 8);
        *reinterpret_cast<bf16x8*>(d + off * 8) = v;
    }
}

// ---------------------------------------------------------------------------
// RoPE epilogue helpers. rope4_tab uses the precomputed table (new path);
// rope4 computes trig directly (legacy fallback path).
// ---------------------------------------------------------------------------
static __device__ __forceinline__ void rope4_tab(const float2* __restrict__ tab,
                                                 const float (&vals)[4], float (&outv)[4],
                                                 int m, int l16) {
    const int s = m & (S_LEN - 1);
#pragma unroll
    for (int nt = 0; nt < 4; ++nt) {
        const int d = nt * 16 + l16;
        const float2 cs = tab[s * 32 + (d & 31)];
        const float part = vals[nt ^ 2];
        const float rot = (nt < 2) ? -part : part;  // d<32: -x2 ; d>=32: +x1
        outv[nt] = vals[nt] * cs.x + rot * cs.y;
    }
}

static __device__ __forceinline__ void rope4(const float (&vals)[4], float (&outv)[4],
                                             int m, int l16) {
    const float sf = (float)(m & (S_LEN - 1));
#pragma unroll
    for (int nt = 0; nt < 4; ++nt) {
        const int d = nt * 16 + l16;
        const float inv = exp2f(-(float)(d & 31) * 0.4152410118609203f);
        const float th = sf * inv;
        float sn, cs;
        sincosf(th, &sn, &cs);
        const float part = vals[nt ^ 2];
        const float rot = (nt < 2) ? -part : part;
        outv[nt] = vals[nt] * cs + rot * sn;
    }
}

// ---------------------------------------------------------------------------
// Fused QKV GEMM (m97 structure): A[4096,2048] @ Wqkv[3072,2048]^T, all bf16.
// 128x128 tile, BK=32, 4 waves 2x2, global_load_lds width=16, XCD swizzle.
// Epilogue routes each wave's head-aligned 64-col span: cols<2048 -> Q
// (d_out, stride 2048, RoPE); 2048..2559 -> K half of kvbuf (stride 1024,
// RoPE); >=2560 -> V half (no RoPE).
// ---------------------------------------------------------------------------
__global__ __launch_bounds__(256) void gemm_qkv_lds(const unsigned short* __restrict__ A,
                                                    const unsigned short* __restrict__ W,
                                                    unsigned short* __restrict__ Qo,
                                                    unsigned short* __restrict__ KVo,
                                                    const float2* __restrict__ ropetab) {
    __shared__ unsigned short lds_a[128 * 32];   // 8KB
    __shared__ unsigned short lds_b[128 * 32];   // 8KB

    const int wave = threadIdx.x >> 6;
    const int lane = threadIdx.x & 63;
    const int l16  = lane & 15;
    const int quad = lane >> 4;
    const int wm   = wave >> 1;
    const int wn   = wave & 1;

    int bx, by;
    xcd_swz(bx, by);
    const int m0 = bx * 128;
    const int n0 = by * 128;

    const int srow = lane >> 2;
    const int scol = (lane & 3) * 8;
    const unsigned short* ag[2];
    const unsigned short* wg[2];
#pragma unroll
    for (int i = 0; i < 2; ++i) {
        const int c = wave * 2 + i;
        ag[i] = A + (size_t)(m0 + c * 16 + srow) * D_MODEL + scol;
        wg[i] = W + (size_t)(n0 + c * 16 + srow) * D_MODEL + scol;
    }

    f32x4 acc[4][4];
#pragma unroll
    for (int i = 0; i < 4; ++i)
#pragma unroll
        for (int j = 0; j < 4; ++j) acc[i][j] = (f32x4){0.f, 0.f, 0.f, 0.f};

    for (int k0 = 0; k0 < D_MODEL; k0 += 32) {
#pragma unroll
        for (int i = 0; i < 2; ++i) {
            const int c = wave * 2 + i;
            GLOAD_LDS16(ag[i] + k0, &lds_a[c * 512]);
            GLOAD_LDS16(wg[i] + k0, &lds_b[c * 512]);
        }
        __syncthreads();

        bf16x8 af[4], bfm[4];
#pragma unroll
        for (int t = 0; t < 4; ++t) {
            af[t]  = *reinterpret_cast<const bf16x8*>(&lds_a[(wm * 64 + t * 16 + l16) * 32 + quad * 8]);
            bfm[t] = *reinterpret_cast<const bf16x8*>(&lds_b[(wn * 64 + t * 16 + l16) * 32 + quad * 8]);
        }
#pragma unroll
        for (int mt = 0; mt < 4; ++mt)
#pragma unroll
            for (int nt = 0; nt < 4; ++nt)
                acc[mt][nt] = MFMA16(af[mt], bfm[nt], acc[mt][nt]);
        __syncthreads();
    }

    const int ncol0 = n0 + wn * 64;                 // wave-uniform, head-aligned
    const bool do_rope = (ncol0 < 2048 + KVW);      // Q and K regions
    unsigned short* dst;
    int cstride, c0;
    if (ncol0 < 2048) { dst = Qo;  cstride = 2048; c0 = ncol0; }
    else              { dst = KVo; cstride = 1024; c0 = ncol0 - 2048; }

#pragma unroll
    for (int mt = 0; mt < 4; ++mt) {
#pragma unroll
        for (int r = 0; r < 4; ++r) {
            const int m = m0 + wm * 64 + mt * 16 + quad * 4 + r;
            float vals[4];
#pragma unroll
            for (int nt = 0; nt < 4; ++nt) vals[nt] = acc[mt][nt][r];
            float outv[4];
            if (do_rope) {
                rope4_tab(ropetab, vals, outv, m, l16);
            } else {
#pragma unroll
                for (int nt = 0; nt < 4; ++nt) outv[nt] = vals[nt];
            }
            unsigned short* cp = dst + (size_t)m * cstride + c0;
#pragma unroll
            for (int nt = 0; nt < 4; ++nt) cp[nt * 16 + l16] = f2bf(outv[nt]);
        }
    }
}

// ---------------------------------------------------------------------------
// LDS-staged GEMM (m97 structure): C[M,N] = A[M,2048] @ W[N,2048]^T, bf16,
// XCD swizzle. Used for the O-projection (rope=0). finalout + f32 input ->
// f32 output. hdet = original hidden buffer for dtype self-detection.
// ---------------------------------------------------------------------------
__global__ __launch_bounds__(256) void gemm_bt_lds(const unsigned short* __restrict__ A,
                                                   const unsigned short* __restrict__ W,
                                                   void* __restrict__ Cp, int N,
                                                   const unsigned short* __restrict__ hdet,
                                                   int rope, int finalout) {
    __shared__ unsigned short lds_a[128 * 32];
    __shared__ unsigned short lds_b[128 * 32];

    bool of32 = false;
    if (finalout) of32 = detect_f32_block(hdet);

    const int wave = threadIdx.x >> 6;
    const int lane = threadIdx.x & 63;
    const int l16  = lane & 15;
    const int quad = lane >> 4;
    const int wm   = wave >> 1;
    const int wn   = wave & 1;

    int bx, by;
    xcd_swz(bx, by);
    const int m0 = bx * 128;
    const int n0 = by * 128;

    const int srow = lane >> 2;
    const int scol = (lane & 3) * 8;
    const unsigned short* ag[2];
    const unsigned short* wg[2];
#pragma unroll
    for (int i = 0; i < 2; ++i) {
        const int c = wave * 2 + i;
        ag[i] = A + (size_t)(m0 + c * 16 + srow) * D_MODEL + scol;
        wg[i] = W + (size_t)(n0 + c * 16 + srow) * D_MODEL + scol;
    }

    f32x4 acc[4][4];
#pragma unroll
    for (int i = 0; i < 4; ++i)
#pragma unroll
        for (int j = 0; j < 4; ++j) acc[i][j] = (f32x4){0.f, 0.f, 0.f, 0.f};

    for (int k0 = 0; k0 < D_MODEL; k0 += 32) {
#pragma unroll
        for (int i = 0; i < 2; ++i) {
            const int c = wave * 2 + i;
            GLOAD_LDS16(ag[i] + k0, &lds_a[c * 512]);
            GLOAD_LDS16(wg[i] + k0, &lds_b[c * 512]);
        }
        __syncthreads();

        bf16x8 af[4], bfm[4];
#pragma unroll
        for (int t = 0; t < 4; ++t) {
            af[t]  = *reinterpret_cast<const bf16x8*>(&lds_a[(wm * 64 + t * 16 + l16) * 32 + quad * 8]);
            bfm[t] = *reinterpret_cast<const bf16x8*>(&lds_b[(wn * 64 + t * 16 + l16) * 32 + quad * 8]);
        }
#pragma unroll
        for (int mt = 0; mt < 4; ++mt)
#pragma unroll
            for (int nt = 0; nt < 4; ++nt)
                acc[mt][nt] = MFMA16(af[mt], bfm[nt], acc[mt][nt]);
        __syncthreads();
    }

    const bool do_rope = (rope != 0);
    const int ncol0 = n0 + wn * 64;

#pragma unroll
    for (int mt = 0; mt < 4; ++mt) {
#pragma unroll
        for (int r = 0; r < 4; ++r) {
            const int m = m0 + wm * 64 + mt * 16 + quad * 4 + r;
            float vals[4];
#pragma unroll
            for (int nt = 0; nt < 4; ++nt) vals[nt] = acc[mt][nt][r];
            float outv[4];
            if (do_rope) {
                rope4(vals, outv, m, l16);
            } else {
#pragma unroll
                for (int nt = 0; nt < 4; ++nt) outv[nt] = vals[nt];
            }
            const size_t crow = (size_t)m * N + ncol0;
            if (of32) {
                float* cp = (float*)Cp + crow;
#pragma unroll
                for (int nt = 0; nt < 4; ++nt) cp[nt * 16 + l16] = outv[nt];
            } else {
                unsigned short* cp = (unsigned short*)Cp + crow;
#pragma unroll
                for (int nt = 0; nt < 4; ++nt) cp[nt * 16 + l16] = f2bf(outv[nt]);
            }
        }
    }
}

// ---------------------------------------------------------------------------
// V transpose: Vsrc = kvbuf V-half [B*S rows, stride 1024] cols 0..511
//   -> Vt[b][c][s] ([B][512][S]).  64x64 LDS tiles, fully coalesced.
// ---------------------------------------------------------------------------
__global__ __launch_bounds__(256) void transpose_v(const unsigned short* __restrict__ Vsrc,
                                                   unsigned short* __restrict__ Vt) {
    __shared__ unsigned short t[64][72];
    const int bid = blockIdx.x;
    const int ct = bid & 7;
    const int st = (bid >> 3) & 31;
    const int b  = bid >> 8;
    const unsigned short* src = Vsrc + ((size_t)b * S_LEN + st * 64) * 1024 + ct * 64;
    unsigned short* dst = Vt + ((size_t)b * KVW + ct * 64) * S_LEN + st * 64;
    const int r0 = threadIdx.x >> 3;
    const int c0 = (threadIdx.x & 7) * 8;
#pragma unroll
    for (int h = 0; h < 2; ++h) {
        bf16x8 v = *reinterpret_cast<const bf16x8*>(src + (size_t)(r0 + h * 32) * 1024 + c0);
        *reinterpret_cast<bf16x8*>(&t[r0 + h * 32][c0]) = v;
    }
    __syncthreads();
#pragma unroll
    for (int h = 0; h < 2; ++h) {
        const int cr = r0 + h * 32;
        bf16x8 v;
#pragma unroll
        for (int j = 0; j < 8; ++j) v[j] = (short)t[c0 + j][cr];
        *reinterpret_cast<bf16x8*>(dst + (size_t)cr * S_LEN + c0) = v;
    }
}

// ---------------------------------------------------------------------------
// Flash attention v6: round-4 verified body (K dbuf, vf-early, deferred max
// THR=8, row-sum via MFMA), now at 3 waves/SIMD: launch_bounds(256,3) caps
// VGPR at 170; grid 1024 (one 128-row q-tile per block, heavy tiles first)
// gives 3 resident blocks/CU -> +50% latency hiding vs round 7's 2/CU.
// ---------------------------------------------------------------------------
struct AttnCtx {
    const unsigned short* qbase;
    const unsigned short* kbase;
    const unsigned short* vtbase;
    unsigned short* obase;
    int kvs;
    int l16, quad;
    unsigned short (*lpw)[72];   // [32][72] per-wave slice
};

#define SM_C 0.18033688011112042f   // 0.125 * log2(e)
#define SM_THR 8.0f

static __device__ __forceinline__ void attn_qtile(const AttnCtx& cx, int q0w) {
    const int l16 = cx.l16, quad = cx.quad;
    const int kvs = cx.kvs;

    bf16x8 ones;
#pragma unroll
    for (int j = 0; j < 8; ++j) ones[j] = (short)0x3F80;   // bf16 1.0

    bf16x8 aq[2][2];
#pragma unroll
    for (int m = 0; m < 2; ++m)
#pragma unroll
        for (int kh = 0; kh < 2; ++kh)
            aq[m][kh] = *reinterpret_cast<const bf16x8*>(
                cx.qbase + (size_t)(q0w + m * 16 + l16) * D_MODEL + kh * 32 + quad * 8);

    f32x4 o[2][4];
    f32x4 c_l[2];     // row-sum accumulator (l = P @ ones)
#pragma unroll
    for (int m = 0; m < 2; ++m) {
#pragma unroll
        for (int i = 0; i < 4; ++i) o[m][i] = (f32x4){0.f, 0.f, 0.f, 0.f};
        c_l[m] = (f32x4){0.f, 0.f, 0.f, 0.f};
    }
    float m2[2][4];   // running max, log2 domain
#pragma unroll
    for (int m = 0; m < 2; ++m)
#pragma unroll
        for (int r = 0; r < 4; ++r) m2[m][r] = 0.f;

    const int kv_hi = q0w + 32;   // per-wave causal bound

    bf16x8 kfa[8], kfb[8];        // K frags [t*2+kh], double-buffered

#define LOADK(DST, KK0)                                                       \
    {                                                                         \
        _Pragma("unroll")                                                     \
        for (int t = 0; t < 4; ++t) {                                         \
            const unsigned short* krow =                                      \
                cx.kbase + (size_t)((KK0) + t * 16 + l16) * kvs;              \
            DST[2 * t]     = *reinterpret_cast<const bf16x8*>(krow + quad * 8);       \
            DST[2 * t + 1] = *reinterpret_cast<const bf16x8*>(krow + 32 + quad * 8);  \
        }                                                                     \
    }

#define ATTN_BODY(CUR, NXT)                                                   \
    {                                                                         \
        f32x4 sc[2][4];                                                       \
        __builtin_amdgcn_s_setprio(1);                                        \
        _Pragma("unroll")                                                     \
        for (int t = 0; t < 4; ++t) {                                         \
            _Pragma("unroll")                                                 \
            for (int m = 0; m < 2; ++m) {                                     \
                f32x4 c = (f32x4){0.f, 0.f, 0.f, 0.f};                        \
                c = MFMA16(aq[m][0], CUR[2 * t], c);                          \
                c = MFMA16(aq[m][1], CUR[2 * t + 1], c);                      \
                sc[m][t] = c;                                                 \
            }                                                                 \
        }                                                                     \
        __builtin_amdgcn_s_setprio(0);                                        \
        if (k0 + 64 < kv_hi) LOADK(NXT, k0 + 64);                             \
        bf16x8 vf[8];                                                         \
        _Pragma("unroll")                                                     \
        for (int nt = 0; nt < 4; ++nt) {                                      \
            const unsigned short* vrow =                                      \
                cx.vtbase + (size_t)(nt * 16 + l16) * S_LEN + k0 + quad * 8;  \
            vf[2 * nt]     = *reinterpret_cast<const bf16x8*>(vrow);          \
            vf[2 * nt + 1] = *reinterpret_cast<const bf16x8*>(vrow + 32);     \
        }                                                                     \
        const bool full = (k0 + 63 <= q0w);                                   \
        float pm[2][4];                                                       \
        float dif = -3.0e38f;                                                 \
        _Pragma("unroll")                                                     \
        for (int m = 0; m < 2; ++m) {                                         \
            _Pragma("unroll")                                                 \
            for (int r = 0; r < 4; ++r) {                                     \
                const int qi = q0w + m * 16 + quad * 4 + r;                   \
                float s[4];                                                   \
                _Pragma("unroll")                                             \
                for (int t = 0; t < 4; ++t) {                                 \
                    s[t] = sc[m][t][r] * SM_C;                                \
                    if (!full && (k0 + t * 16 + l16 > qi)) s[t] = -1.0e30f;   \
                    sc[m][t][r] = s[t];                                       \
                }                                                             \
                const float p = fmaxf(fmaxf(s[0], s[1]), fmaxf(s[2], s[3])); \
                pm[m][r] = p;                                                 \
                dif = fmaxf(dif, p - m2[m][r]);                               \
            }                                                                 \
        }                                                                     \
        if (__any(dif > SM_THR)) {                                            \
            _Pragma("unroll")                                                 \
            for (int m = 0; m < 2; ++m) {                                     \
                _Pragma("unroll")                                             \
                for (int r = 0; r < 4; ++r) {                                 \
                    float mt = pm[m][r];                                      \
                    _Pragma("unroll")                                         \
                    for (int off = 1; off < 16; off <<= 1)                    \
                        mt = fmaxf(mt, __shfl_xor(mt, off, 64));              \
                    const float mn = fmaxf(m2[m][r], mt);                     \
                    const float al = fexp2(m2[m][r] - mn);                    \
                    m2[m][r] = mn;                                            \
                    _Pragma("unroll")                                         \
                    for (int nt = 0; nt < 4; ++nt) o[m][nt][r] *= al;         \
                    c_l[m][r] *= al;                                          \
                }                                                             \
            }                                                                 \
        }                                                                     \
        /* pass 2: p = 2^(s - m2), write P tile */                            \
        _Pragma("unroll")                                                     \
        for (int m = 0; m < 2; ++m) {                                         \
            _Pragma("unroll")                                                 \
            for (int r = 0; r < 4; ++r) {                                     \
                const float mb = m2[m][r];                                    \
                _Pragma("unroll")                                             \
                for (int t = 0; t < 4; ++t) {                                 \
                    const float pv = fexp2(sc[m][t][r] - mb);                 \
                    cx.lpw[m * 16 + quad * 4 + r][t * 16 + l16] = f2bf(pv);   \
                }                                                             \
            }                                                                 \
        }                                                                     \
        asm volatile("" ::: "memory");                                        \
        bf16x8 ap[2][2];                                                      \
        _Pragma("unroll")                                                     \
        for (int m = 0; m < 2; ++m)                                           \
            _Pragma("unroll")                                                 \
            for (int kh = 0; kh < 2; ++kh)                                    \
                ap[m][kh] = *reinterpret_cast<const bf16x8*>(                 \
                    &cx.lpw[m * 16 + l16][kh * 32 + quad * 8]);               \
        __builtin_amdgcn_s_setprio(1);                                        \
        _Pragma("unroll")                                                     \
        for (int nt = 0; nt < 4; ++nt)                                        \
            _Pragma("unroll")                                                 \
            for (int m = 0; m < 2; ++m) {                                     \
                o[m][nt] = MFMA16(ap[m][0], vf[2 * nt], o[m][nt]);            \
                o[m][nt] = MFMA16(ap[m][1], vf[2 * nt + 1], o[m][nt]);        \
            }                                                                 \
        _Pragma("unroll")                                                     \
        for (int m = 0; m < 2; ++m) {                                         \
            c_l[m] = MFMA16(ap[m][0], ones, c_l[m]);                          \
            c_l[m] = MFMA16(ap[m][1], ones, c_l[m]);                          \
        }                                                                     \
        __builtin_amdgcn_s_setprio(0);                                        \
    }

    LOADK(kfa, 0);
    int k0 = 0;
    for (;;) {
        ATTN_BODY(kfa, kfb);
        k0 += 64;
        if (k0 >= kv_hi) break;
        ATTN_BODY(kfb, kfa);
        k0 += 64;
        if (k0 >= kv_hi) break;
    }
#undef ATTN_BODY
#undef LOADK

#pragma unroll
    for (int m = 0; m < 2; ++m)
#pragma unroll
        for (int r = 0; r < 4; ++r) {
            const float inv_l = 1.0f / c_l[m][r];
            unsigned short* orow = cx.obase + (size_t)(q0w + m * 16 + quad * 4 + r) * D_MODEL;
#pragma unroll
            for (int nt = 0; nt < 4; ++nt)
                orow[nt * 16 + l16] = f2bf(o[m][nt][r] * inv_l);
        }
}

__global__ __launch_bounds__(256, 3) void attn_kernel6(const unsigned short* __restrict__ Q,
                                                       const unsigned short* __restrict__ Kb,
                                                       const unsigned short* __restrict__ Vt,
                                                       unsigned short* __restrict__ O, int kvs) {
    __shared__ unsigned short lp[4][32][72];   // per-wave P (32 q x 64 k), padded

    const int wave = threadIdx.x >> 6;
    const int lane = threadIdx.x & 63;

    const int bid = blockIdx.x;
    const int qt  = 15 - (bid & 15);            // heavy q-tiles dispatch first
    const int h   = (bid >> 4) & (NHEAD - 1);
    const int b   = bid >> 9;
    const int kvh = h >> 2;

    AttnCtx cx;
    cx.qbase  = Q + (size_t)b * S_LEN * D_MODEL + h * HEAD_DIM;
    cx.kbase  = Kb + (size_t)b * S_LEN * kvs + kvh * HEAD_DIM;
    cx.vtbase = Vt + ((size_t)b * KVW + kvh * HEAD_DIM) * S_LEN;
    cx.obase  = O + (size_t)b * S_LEN * D_MODEL + h * HEAD_DIM;
    cx.kvs    = kvs;
    cx.l16    = lane & 15;
    cx.quad   = lane >> 4;
    cx.lpw    = lp[wave];

    attn_qtile(cx, qt * 128 + wave * 32);
}

// ---------------------------------------------------------------------------
// Legacy direct-load GEMM + attention (fallback path only).
// ---------------------------------------------------------------------------
__global__ __launch_bounds__(256) void gemm_bt(const void* __restrict__ Ap,
                                               const void* __restrict__ Wp,
                                               void* __restrict__ Cp, int N,
                                               const unsigned short* __restrict__ hdet,
                                               int a_input, int rope, int finalout) {
    const bool isf32 = detect_f32_block(hdet);
    const bool af32 = isf32 && (a_input != 0);
    const bool wf32 = isf32;
    const bool of32 = isf32 && (finalout != 0);

    const int wave = threadIdx.x >> 6;
    const int lane = threadIdx.x & 63;
    const int l16  = lane & 15;
    const int quad = lane >> 4;
    const int m0 = blockIdx.x * 64 + wave * 16;
    const int n0 = blockIdx.y * 64;

    f32x4 acc[4];
#pragma unroll
    for (int i = 0; i < 4; ++i) acc[i] = (f32x4){0.f, 0.f, 0.f, 0.f};

    const size_t aoff = (size_t)(m0 + l16) * D_MODEL + quad * 8;
    size_t woff[4];
#pragma unroll
    for (int nt = 0; nt < 4; ++nt)
        woff[nt] = (size_t)(n0 + nt * 16 + l16) * D_MODEL + quad * 8;

    for (int k0 = 0; k0 < D_MODEL; k0 += 32) {
        bf16x8 a = load_frag(af32, Ap, aoff + k0);
#pragma unroll
        for (int nt = 0; nt < 4; ++nt) {
            bf16x8 b = load_frag(wf32, Wp, woff[nt] + k0);
            acc[nt] = MFMA16(a, b, acc[nt]);
        }
    }

#pragma unroll
    for (int r = 0; r < 4; ++r) {
        const int m = m0 + quad * 4 + r;
        float vals[4];
#pragma unroll
        for (int nt = 0; nt < 4; ++nt) vals[nt] = acc[nt][r];
        float outv[4];
        if (rope) {
            rope4(vals, outv, m, l16);
        } else {
#pragma unroll
            for (int nt = 0; nt < 4; ++nt) outv[nt] = vals[nt];
        }
        const size_t crow = (size_t)m * N + n0;
        if (of32) {
            float* cp = (float*)Cp + crow;
#pragma unroll
            for (int nt = 0; nt < 4; ++nt) cp[nt * 16 + l16] = outv[nt];
        } else {
            unsigned short* cp = (unsigned short*)Cp + crow;
#pragma unroll
            for (int nt = 0; nt < 4; ++nt) cp[nt * 16 + l16] = f2bf(outv[nt]);
        }
    }
}

__global__ __launch_bounds__(256) void attn_kernel(const unsigned short* __restrict__ Q,
                                                   const unsigned short* __restrict__ Kb,
                                                   const unsigned short* __restrict__ Vb,
                                                   unsigned short* __restrict__ O, int kvs) {
    __shared__ unsigned short lp[4][16][32];

    const int wave = threadIdx.x >> 6;
    const int lane = threadIdx.x & 63;
    const int l16  = lane & 15;
    const int quad = lane >> 4;

    const int bid = blockIdx.x;
    const int qb  = bid & 31;
    const int h   = (bid >> 5) & 31;
    const int b   = bid >> 10;
    const int kvh = h >> 2;
    const int q0  = qb * 64 + wave * 16;

    const unsigned short* qbase = Q + (size_t)b * S_LEN * D_MODEL + h * HEAD_DIM;
    const unsigned short* kbase = Kb + (size_t)b * S_LEN * kvs + kvh * HEAD_DIM;
    const unsigned short* vbase = Vb + (size_t)b * S_LEN * kvs + kvh * HEAD_DIM;

    bf16x8 aq0 = *reinterpret_cast<const bf16x8*>(qbase + (size_t)(q0 + l16) * D_MODEL + quad * 8);
    bf16x8 aq1 = *reinterpret_cast<const bf16x8*>(qbase + (size_t)(q0 + l16) * D_MODEL + 32 + quad * 8);

    f32x4 o[4];
#pragma unroll
    for (int i = 0; i < 4; ++i) o[i] = (f32x4){0.f, 0.f, 0.f, 0.f};
    float mrow[4], lrow[4];
#pragma unroll
    for (int r = 0; r < 4; ++r) { mrow[r] = -3.0e38f; lrow[r] = 0.f; }

    const int kv_hi = qb * 64 + 64;
    for (int k0 = 0; k0 < kv_hi; k0 += 32) {
        f32x4 sc[2];
#pragma unroll
        for (int t = 0; t < 2; ++t) {
            const unsigned short* krow = kbase + (size_t)(k0 + t * 16 + l16) * kvs;
            bf16x8 b0 = *reinterpret_cast<const bf16x8*>(krow + quad * 8);
            bf16x8 b1 = *reinterpret_cast<const bf16x8*>(krow + 32 + quad * 8);
            f32x4 c = (f32x4){0.f, 0.f, 0.f, 0.f};
            c = MFMA16(aq0, b0, c);
            c = MFMA16(aq1, b1, c);
            sc[t] = c;
        }

        float alpha[4], p0v[4], p1v[4];
#pragma unroll
        for (int r = 0; r < 4; ++r) {
            const int qi = q0 + quad * 4 + r;
            float s0 = sc[0][r] * 0.125f;
            float s1 = sc[1][r] * 0.125f;
            if (k0 + l16 > qi)       s0 = -1.0e30f;
            if (k0 + 16 + l16 > qi)  s1 = -1.0e30f;
            float mt = fmaxf(s0, s1);
#pragma unroll
            for (int off = 1; off < 16; off <<= 1) mt = fmaxf(mt, __shfl_xor(mt, off, 64));
            const float mn = fmaxf(mrow[r], mt);
            const float al = __expf(mrow[r] - mn);
            const float p0 = __expf(s0 - mn);
            const float p1 = __expf(s1 - mn);
            float rs = p0 + p1;
#pragma unroll
            for (int off = 1; off < 16; off <<= 1) rs += __shfl_xor(rs, off, 64);
            lrow[r] = lrow[r] * al + rs;
            mrow[r] = mn;
            alpha[r] = al;
            p0v[r] = p0; p1v[r] = p1;
        }
#pragma unroll
        for (int nt = 0; nt < 4; ++nt)
#pragma unroll
            for (int r = 0; r < 4; ++r) o[nt][r] *= alpha[r];

        __syncthreads();
#pragma unroll
        for (int r = 0; r < 4; ++r) {
            lp[wave][quad * 4 + r][l16]      = f2bf(p0v[r]);
            lp[wave][quad * 4 + r][16 + l16] = f2bf(p1v[r]);
        }
        __syncthreads();
        bf16x8 ap = *reinterpret_cast<const bf16x8*>(&lp[wave][l16][quad * 8]);

#pragma unroll
        for (int nt = 0; nt < 4; ++nt) {
            const unsigned short* vcol = vbase + nt * 16 + l16 + (size_t)(k0 + quad * 8) * kvs;
            bf16x8 bv;
#pragma unroll
            for (int j = 0; j < 8; ++j) bv[j] = (short)vcol[(size_t)j * kvs];
            o[nt] = MFMA16(ap, bv, o[nt]);
        }
    }

    unsigned short* obase = O + (size_t)b * S_LEN * D_MODEL + h * HEAD_DIM;
#pragma unroll
    for (int r = 0; r < 4; ++r) {
        const float inv_l = 1.0f / lrow[r];
        unsigned short* orow = obase + (size_t)(q0 + quad * 4 + r) * D_MODEL;
#pragma unroll
        for (int nt = 0; nt < 4; ++nt)
            orow[nt * 16 + l16] = f2bf(o[nt][r] * inv_l);
    }
}

extern "C" void kernel_launch(void* const* d_in, const int* in_sizes, int n_in,
                              void* d_out, int out_size, void* d_ws, size_t ws_size,
                              hipStream_t stream) {
    const void* hidden = d_in[0];
    const void* Wq = d_in[1];
    const void* Wk = d_in[2];
    const void* Wv = d_in[3];
    const void* Wo = d_in[4];
    // d_in[5] = attention_mask: pure causal -1e9 -> implemented directly.

    char* ws = (char*)d_ws;
    dim3 blk(256);

    // kv 8MB + abuf 16MB + hbuf 16MB + wq 8MB + wkv 4MB + wo 8MB + vt 4MB + tab 512KB
    const size_t NEED = 1024 + ((size_t)64 << 20) + (512u << 10);
    if (ws_size >= NEED) {
        unsigned short* kvbuf = (unsigned short*)(ws + 1024);      // [4096,1024]: K cols 0-511, V cols 512-1023
        unsigned short* abuf  = kvbuf + (size_t)4096 * 1024;       // [4096,2048]
        unsigned short* hbuf  = abuf + (size_t)4096 * 2048;        // hidden bf16
        unsigned short* wqb   = hbuf + (size_t)4096 * 2048;        // [2048,2048]  } contiguous =
        unsigned short* wkvb  = wqb + (size_t)2048 * 2048;         // [1024,2048]  } Wqkv [3072,2048]
        unsigned short* wob   = wkvb + (size_t)1024 * 2048;        // [2048,2048]
        unsigned short* vtbuf = wob + (size_t)2048 * 2048;         // [2,512,2048] V^T
        float2* ropetab       = (float2*)(vtbuf + (size_t)2 * 512 * 2048);  // [2048][32]
        unsigned short* qbuf  = (unsigned short*)d_out;            // Q bf16 lives in d_out

        cvt_all<<<dim3(2048), blk, 0, stream>>>(hidden, Wq, Wk, Wv, Wo,
                                                hbuf, wqb, wkvb, wob, ropetab);

        gemm_qkv_lds<<<dim3(32, 24), blk, 0, stream>>>(hbuf, wqb, qbuf, kvbuf, ropetab);
        transpose_v<<<dim3(512), blk, 0, stream>>>(kvbuf + 512, vtbuf);
        attn_kernel6<<<dim3(2 * NHEAD * (S_LEN / 128)), blk, 0, stream>>>(qbuf, kvbuf, vtbuf, abuf, 1024);
        gemm_bt_lds<<<dim3(32, 16), blk, 0, stream>>>(abuf, wob, d_out, 2048,
                                                      (const unsigned short*)hidden, 0, 1);
    } else {
        // legacy 24MB path
        unsigned short* kbuf = (unsigned short*)(ws + 1024);
        unsigned short* vbuf = (unsigned short*)(ws + 1024 + (4u << 20));
        unsigned short* abuf = (unsigned short*)(ws + 1024 + (8u << 20));
        unsigned short* qbuf = (unsigned short*)d_out;
        const unsigned short* hdet = (const unsigned short*)hidden;
        gemm_bt<<<dim3(M_ROWS / 64, D_MODEL / 64), blk, 0, stream>>>(hidden, Wq, qbuf, D_MODEL, hdet, 1, 1, 0);
        gemm_bt<<<dim3(M_ROWS / 64, (NKVH * HEAD_DIM) / 64), blk, 0, stream>>>(hidden, Wk, kbuf, NKVH * HEAD_DIM, hdet, 1, 1, 0);
        gemm_bt<<<dim3(M_ROWS / 64, (NKVH * HEAD_DIM) / 64), blk, 0, stream>>>(hidden, Wv, vbuf, NKVH * HEAD_DIM, hdet, 1, 0, 0);
        attn_kernel<<<dim3(2 * NHEAD * (S_LEN / 64)), blk, 0, stream>>>(qbuf, kbuf, vbuf, abuf, 512);
        gemm_bt<<<dim3(M_ROWS / 64, D_MODEL / 64), blk, 0, stream>>>(abuf, Wo, d_out, D_MODEL, hdet, 0, 0, 1);
    }
}

// Round 9
// 426.160 us; speedup vs baseline: 2.6247x; 2.6247x over previous
//
#include <hip/hip_runtime.h>

// FlashAttentionWrapper: B=2, S=2048, D=2048, NH=32, HD=64, NKV=8, NREP=4,
// causal, RoPE theta=1e4. Input dtype (bf16/f32) self-detected per block.
// New-path workspace (64MB+1KB+512KB):
//   [1KB pad][kvbuf 4096x1024 8MB][abuf 4096x2048 16MB]
//   [hbuf 16MB][wqb 8MB][wkvb 4MB][wob 8MB][vtbuf 2x512x2048 4MB]
//   [ropetab 2048x32 float2 512KB]
// wqb+wkvb are CONTIGUOUS => one [3072,2048] QKV weight matrix (fused GEMM).
// Q-projection result lives in d_out (dead before O-proj overwrites it).
// Fallback path (ws too small): original direct-load kernels, 24MB+1KB.
//
// Round-5 lesson: hand-written v_cvt_pk_bf16_f32 asm mis-packed (absmax 3.6).
// Round-8 lesson: __launch_bounds__(256,3) forced VGPR 184->84 => massive
// scratch spill (hbm_bytes 32x, 833us). Round-9: reduce live state
// STRUCTURALLY (single-buffered K; kf regs reused for vf) so natural VGPR
// lands <=170 (3 waves/SIMD), grid 1024 globally-heavy-first for 3 blocks/CU.

#define S_LEN 2048
#define D_MODEL 2048
#define NHEAD 32
#define HEAD_DIM 64
#define NKVH 8
#define M_ROWS 4096   // B*S
#define KVW (NKVH * HEAD_DIM)   // 512

typedef __attribute__((ext_vector_type(4))) float f32x4;
typedef __attribute__((ext_vector_type(8))) short bf16x8;

#define MFMA16(a, b, c) __builtin_amdgcn_mfma_f32_16x16x32_bf16((a), (b), (c), 0, 0, 0)

// async global->LDS, 16B per lane; LDS dest is wave-uniform base + lane*16
#define GLOAD_LDS16(g, l)                                                     \
    __builtin_amdgcn_global_load_lds(                                         \
        (const __attribute__((address_space(1))) void*)(g),                   \
        (__attribute__((address_space(3))) void*)(l), 16, 0, 0)

// f32 -> bf16 RNE via native cast (compiler emits the HW convert).
static __device__ __forceinline__ unsigned short f2bf(float f) {
    union { __bf16 b; unsigned short u; } v;
    v.b = (__bf16)f;
    return v.u;
}

static __device__ __forceinline__ float fexp2(float x) {
#if __has_builtin(__builtin_amdgcn_exp2f)
    return __builtin_amdgcn_exp2f(x);
#else
    return exp2f(x);
#endif
}

// XCD-chunked swizzle of a 2D grid (requires gridDim.x*gridDim.y % 8 == 0).
static __device__ __forceinline__ void xcd_swz(int& bx, int& by) {
    const int gx = gridDim.x;
    const int nwg = gx * gridDim.y;
    int lin = blockIdx.y * gx + blockIdx.x;
    lin = (lin & 7) * (nwg >> 3) + (lin >> 3);
    bx = lin % gx;
    by = lin / gx;
}

// ---------------------------------------------------------------------------
// Per-block dtype self-detection: f32 data read as uint16 shows impossible
// bf16 exponents at even indices. Called uniformly by all 256 threads.
// ---------------------------------------------------------------------------
static __device__ bool detect_f32_block(const unsigned short* __restrict__ h) {
    __shared__ int dcnt;
    if (threadIdx.x == 0) dcnt = 0;
    __syncthreads();
    const unsigned short v = h[2 * (threadIdx.x & 255)];
    const int e = (v >> 7) & 0xFF;
    if (threadIdx.x < 256 && e >= 0x8D) atomicAdd(&dcnt, 1);
    __syncthreads();
    return dcnt >= 8;
}

static __device__ __forceinline__ bf16x8 load_frag(bool f32p, const void* p, size_t off) {
    if (f32p) {
        const float* fp = (const float*)p + off;
        f32x4 x = *reinterpret_cast<const f32x4*>(fp);
        f32x4 y = *reinterpret_cast<const f32x4*>(fp + 4);
        bf16x8 r;
        r[0] = (short)f2bf(x[0]); r[1] = (short)f2bf(x[1]);
        r[2] = (short)f2bf(x[2]); r[3] = (short)f2bf(x[3]);
        r[4] = (short)f2bf(y[0]); r[5] = (short)f2bf(y[1]);
        r[6] = (short)f2bf(y[2]); r[7] = (short)f2bf(y[3]);
        return r;
    }
    return *reinterpret_cast<const bf16x8*>((const unsigned short*)p + off);
}

// ---------------------------------------------------------------------------
// Fused one-time f32->bf16 conversion (or bf16 copy) of all 5 operands,
// plus the RoPE cos/sin table (tab[s*32+dd] = cos/sin of s*10000^(-dd/32)).
// ---------------------------------------------------------------------------
__global__ __launch_bounds__(256) void cvt_all(const void* __restrict__ h,
                                               const void* __restrict__ wq,
                                               const void* __restrict__ wk,
                                               const void* __restrict__ wv,
                                               const void* __restrict__ wo,
                                               unsigned short* __restrict__ hbuf,
                                               unsigned short* __restrict__ wqb,
                                               unsigned short* __restrict__ wkvb,
                                               unsigned short* __restrict__ wob,
                                               float2* __restrict__ ropetab) {
    const bool f32p = detect_f32_block((const unsigned short*)h);
    const int e0 = 1048576;            // hidden 4096x2048
    const int e1 = e0 + 524288;        // Wq 2048x2048
    const int e2 = e1 + 131072;        // Wk 512x2048
    const int e3 = e2 + 131072;        // Wv 512x2048
    const int e4 = e3 + 524288;        // Wo 2048x2048
    const int e5 = e4 + 8192;          // rope table 2048x32 (8 entries/unit)
    int i = blockIdx.x * 256 + threadIdx.x;
    const int stride = gridDim.x * 256;
    for (; i < e5; i += stride) {
        if (i >= e4) {
            const int base = (i - e4) * 8;
#pragma unroll
            for (int j = 0; j < 8; ++j) {
                const int idx = base + j;
                const int s = idx >> 5, dd = idx & 31;
                const float inv = exp2f(-(float)dd * 0.4152410118609203f);
                const float th = (float)s * inv;
                float sn, cs;
                sincosf(th, &sn, &cs);
                ropetab[idx] = make_float2(cs, sn);
            }
            continue;
        }
        const void* s;
        unsigned short* d;
        size_t off;
        if (i < e0)      { s = h;  d = hbuf; off = (size_t)i; }
        else if (i < e1) { s = wq; d = wqb;  off = (size_t)(i - e0); }
        else if (i < e2) { s = wk; d = wkvb; off = (size_t)(i - e1); }
        else if (i < e3) { s = wv; d = wkvb + (size_t)512 * 2048; off = (size_t)(i - e2); }
        else             { s = wo; d = wob;  off = (size_t)(i - e3); }
        bf16x8 v = load_frag(f32p, s, off * 8);
        *reinterpret_cast<bf16x8*>(d + off * 8) = v;
    }
}

// ---------------------------------------------------------------------------
// RoPE epilogue helpers. rope4_tab uses the precomputed table (new path);
// rope4 computes trig directly (legacy fallback path).
// ---------------------------------------------------------------------------
static __device__ __forceinline__ void rope4_tab(const float2* __restrict__ tab,
                                                 const float (&vals)[4], float (&outv)[4],
                                                 int m, int l16) {
    const int s = m & (S_LEN - 1);
#pragma unroll
    for (int nt = 0; nt < 4; ++nt) {
        const int d = nt * 16 + l16;
        const float2 cs = tab[s * 32 + (d & 31)];
        const float part = vals[nt ^ 2];
        const float rot = (nt < 2) ? -part : part;  // d<32: -x2 ; d>=32: +x1
        outv[nt] = vals[nt] * cs.x + rot * cs.y;
    }
}

static __device__ __forceinline__ void rope4(const float (&vals)[4], float (&outv)[4],
                                             int m, int l16) {
    const float sf = (float)(m & (S_LEN - 1));
#pragma unroll
    for (int nt = 0; nt < 4; ++nt) {
        const int d = nt * 16 + l16;
        const float inv = exp2f(-(float)(d & 31) * 0.4152410118609203f);
        const float th = sf * inv;
        float sn, cs;
        sincosf(th, &sn, &cs);
        const float part = vals[nt ^ 2];
        const float rot = (nt < 2) ? -part : part;
        outv[nt] = vals[nt] * cs + rot * sn;
    }
}

// ---------------------------------------------------------------------------
// Fused QKV GEMM (m97 structure): A[4096,2048] @ Wqkv[3072,2048]^T, all bf16.
// 128x128 tile, BK=32, 4 waves 2x2, global_load_lds width=16, XCD swizzle.
// Epilogue routes each wave's head-aligned 64-col span.
// ---------------------------------------------------------------------------
__global__ __launch_bounds__(256) void gemm_qkv_lds(const unsigned short* __restrict__ A,
                                                    const unsigned short* __restrict__ W,
                                                    unsigned short* __restrict__ Qo,
                                                    unsigned short* __restrict__ KVo,
                                                    const float2* __restrict__ ropetab) {
    __shared__ unsigned short lds_a[128 * 32];   // 8KB
    __shared__ unsigned short lds_b[128 * 32];   // 8KB

    const int wave = threadIdx.x >> 6;
    const int lane = threadIdx.x & 63;
    const int l16  = lane & 15;
    const int quad = lane >> 4;
    const int wm   = wave >> 1;
    const int wn   = wave & 1;

    int bx, by;
    xcd_swz(bx, by);
    const int m0 = bx * 128;
    const int n0 = by * 128;

    const int srow = lane >> 2;
    const int scol = (lane & 3) * 8;
    const unsigned short* ag[2];
    const unsigned short* wg[2];
#pragma unroll
    for (int i = 0; i < 2; ++i) {
        const int c = wave * 2 + i;
        ag[i] = A + (size_t)(m0 + c * 16 + srow) * D_MODEL + scol;
        wg[i] = W + (size_t)(n0 + c * 16 + srow) * D_MODEL + scol;
    }

    f32x4 acc[4][4];
#pragma unroll
    for (int i = 0; i < 4; ++i)
#pragma unroll
        for (int j = 0; j < 4; ++j) acc[i][j] = (f32x4){0.f, 0.f, 0.f, 0.f};

    for (int k0 = 0; k0 < D_MODEL; k0 += 32) {
#pragma unroll
        for (int i = 0; i < 2; ++i) {
            const int c = wave * 2 + i;
            GLOAD_LDS16(ag[i] + k0, &lds_a[c * 512]);
            GLOAD_LDS16(wg[i] + k0, &lds_b[c * 512]);
        }
        __syncthreads();

        bf16x8 af[4], bfm[4];
#pragma unroll
        for (int t = 0; t < 4; ++t) {
            af[t]  = *reinterpret_cast<const bf16x8*>(&lds_a[(wm * 64 + t * 16 + l16) * 32 + quad * 8]);
            bfm[t] = *reinterpret_cast<const bf16x8*>(&lds_b[(wn * 64 + t * 16 + l16) * 32 + quad * 8]);
        }
#pragma unroll
        for (int mt = 0; mt < 4; ++mt)
#pragma unroll
            for (int nt = 0; nt < 4; ++nt)
                acc[mt][nt] = MFMA16(af[mt], bfm[nt], acc[mt][nt]);
        __syncthreads();
    }

    const int ncol0 = n0 + wn * 64;                 // wave-uniform, head-aligned
    const bool do_rope = (ncol0 < 2048 + KVW);      // Q and K regions
    unsigned short* dst;
    int cstride, c0;
    if (ncol0 < 2048) { dst = Qo;  cstride = 2048; c0 = ncol0; }
    else              { dst = KVo; cstride = 1024; c0 = ncol0 - 2048; }

#pragma unroll
    for (int mt = 0; mt < 4; ++mt) {
#pragma unroll
        for (int r = 0; r < 4; ++r) {
            const int m = m0 + wm * 64 + mt * 16 + quad * 4 + r;
            float vals[4];
#pragma unroll
            for (int nt = 0; nt < 4; ++nt) vals[nt] = acc[mt][nt][r];
            float outv[4];
            if (do_rope) {
                rope4_tab(ropetab, vals, outv, m, l16);
            } else {
#pragma unroll
                for (int nt = 0; nt < 4; ++nt) outv[nt] = vals[nt];
            }
            unsigned short* cp = dst + (size_t)m * cstride + c0;
#pragma unroll
            for (int nt = 0; nt < 4; ++nt) cp[nt * 16 + l16] = f2bf(outv[nt]);
        }
    }
}

// ---------------------------------------------------------------------------
// LDS-staged GEMM (m97 structure): C[M,N] = A[M,2048] @ W[N,2048]^T, bf16,
// XCD swizzle. Used for the O-projection (rope=0). finalout + f32 input ->
// f32 output. hdet = original hidden buffer for dtype self-detection.
// ---------------------------------------------------------------------------
__global__ __launch_bounds__(256) void gemm_bt_lds(const unsigned short* __restrict__ A,
                                                   const unsigned short* __restrict__ W,
                                                   void* __restrict__ Cp, int N,
                                                   const unsigned short* __restrict__ hdet,
                                                   int rope, int finalout) {
    __shared__ unsigned short lds_a[128 * 32];
    __shared__ unsigned short lds_b[128 * 32];

    bool of32 = false;
    if (finalout) of32 = detect_f32_block(hdet);

    const int wave = threadIdx.x >> 6;
    const int lane = threadIdx.x & 63;
    const int l16  = lane & 15;
    const int quad = lane >> 4;
    const int wm   = wave >> 1;
    const int wn   = wave & 1;

    int bx, by;
    xcd_swz(bx, by);
    const int m0 = bx * 128;
    const int n0 = by * 128;

    const int srow = lane >> 2;
    const int scol = (lane & 3) * 8;
    const unsigned short* ag[2];
    const unsigned short* wg[2];
#pragma unroll
    for (int i = 0; i < 2; ++i) {
        const int c = wave * 2 + i;
        ag[i] = A + (size_t)(m0 + c * 16 + srow) * D_MODEL + scol;
        wg[i] = W + (size_t)(n0 + c * 16 + srow) * D_MODEL + scol;
    }

    f32x4 acc[4][4];
#pragma unroll
    for (int i = 0; i < 4; ++i)
#pragma unroll
        for (int j = 0; j < 4; ++j) acc[i][j] = (f32x4){0.f, 0.f, 0.f, 0.f};

    for (int k0 = 0; k0 < D_MODEL; k0 += 32) {
#pragma unroll
        for (int i = 0; i < 2; ++i) {
            const int c = wave * 2 + i;
            GLOAD_LDS16(ag[i] + k0, &lds_a[c * 512]);
            GLOAD_LDS16(wg[i] + k0, &lds_b[c * 512]);
        }
        __syncthreads();

        bf16x8 af[4], bfm[4];
#pragma unroll
        for (int t = 0; t < 4; ++t) {
            af[t]  = *reinterpret_cast<const bf16x8*>(&lds_a[(wm * 64 + t * 16 + l16) * 32 + quad * 8]);
            bfm[t] = *reinterpret_cast<const bf16x8*>(&lds_b[(wn * 64 + t * 16 + l16) * 32 + quad * 8]);
        }
#pragma unroll
        for (int mt = 0; mt < 4; ++mt)
#pragma unroll
            for (int nt = 0; nt < 4; ++nt)
                acc[mt][nt] = MFMA16(af[mt], bfm[nt], acc[mt][nt]);
        __syncthreads();
    }

    const bool do_rope = (rope != 0);
    const int ncol0 = n0 + wn * 64;

#pragma unroll
    for (int mt = 0; mt < 4; ++mt) {
#pragma unroll
        for (int r = 0; r < 4; ++r) {
            const int m = m0 + wm * 64 + mt * 16 + quad * 4 + r;
            float vals[4];
#pragma unroll
            for (int nt = 0; nt < 4; ++nt) vals[nt] = acc[mt][nt][r];
            float outv[4];
            if (do_rope) {
                rope4(vals, outv, m, l16);
            } else {
#pragma unroll
                for (int nt = 0; nt < 4; ++nt) outv[nt] = vals[nt];
            }
            const size_t crow = (size_t)m * N + ncol0;
            if (of32) {
                float* cp = (float*)Cp + crow;
#pragma unroll
                for (int nt = 0; nt < 4; ++nt) cp[nt * 16 + l16] = outv[nt];
            } else {
                unsigned short* cp = (unsigned short*)Cp + crow;
#pragma unroll
                for (int nt = 0; nt < 4; ++nt) cp[nt * 16 + l16] = f2bf(outv[nt]);
            }
        }
    }
}

// ---------------------------------------------------------------------------
// V transpose: Vsrc = kvbuf V-half [B*S rows, stride 1024] cols 0..511
//   -> Vt[b][c][s] ([B][512][S]).  64x64 LDS tiles, fully coalesced.
// ---------------------------------------------------------------------------
__global__ __launch_bounds__(256) void transpose_v(const unsigned short* __restrict__ Vsrc,
                                                   unsigned short* __restrict__ Vt) {
    __shared__ unsigned short t[64][72];
    const int bid = blockIdx.x;
    const int ct = bid & 7;
    const int st = (bid >> 3) & 31;
    const int b  = bid >> 8;
    const unsigned short* src = Vsrc + ((size_t)b * S_LEN + st * 64) * 1024 + ct * 64;
    unsigned short* dst = Vt + ((size_t)b * KVW + ct * 64) * S_LEN + st * 64;
    const int r0 = threadIdx.x >> 3;
    const int c0 = (threadIdx.x & 7) * 8;
#pragma unroll
    for (int h = 0; h < 2; ++h) {
        bf16x8 v = *reinterpret_cast<const bf16x8*>(src + (size_t)(r0 + h * 32) * 1024 + c0);
        *reinterpret_cast<bf16x8*>(&t[r0 + h * 32][c0]) = v;
    }
    __syncthreads();
#pragma unroll
    for (int h = 0; h < 2; ++h) {
        const int cr = r0 + h * 32;
        bf16x8 v;
#pragma unroll
        for (int j = 0; j < 8; ++j) v[j] = (short)t[c0 + j][cr];
        *reinterpret_cast<bf16x8*>(dst + (size_t)cr * S_LEN + c0) = v;
    }
}

// ---------------------------------------------------------------------------
// Flash attention v7: round-4 verified math (deferred max THR=8, row-sum via
// MFMA, vf-early), SINGLE-buffered K so kf's 32 VGPRs die after QK^T and get
// reused for vf -> natural VGPR ~150 (<=170 => 3 waves/SIMD). Plain
// launch_bounds(256) — no forced occupancy (round-8 spill lesson). Grid 1024,
// globally heavy-first (qt tier = bid>>6) so the longest blocks start first.
// ---------------------------------------------------------------------------
struct AttnCtx {
    const unsigned short* qbase;
    const unsigned short* kbase;
    const unsigned short* vtbase;
    unsigned short* obase;
    int kvs;
    int l16, quad;
    unsigned short (*lpw)[72];   // [32][72] per-wave slice
};

#define SM_C 0.18033688011112042f   // 0.125 * log2(e)
#define SM_THR 8.0f

static __device__ __forceinline__ void attn_qtile(const AttnCtx& cx, int q0w) {
    const int l16 = cx.l16, quad = cx.quad;
    const int kvs = cx.kvs;

    bf16x8 ones;
#pragma unroll
    for (int j = 0; j < 8; ++j) ones[j] = (short)0x3F80;   // bf16 1.0

    bf16x8 aq[2][2];
#pragma unroll
    for (int m = 0; m < 2; ++m)
#pragma unroll
        for (int kh = 0; kh < 2; ++kh)
            aq[m][kh] = *reinterpret_cast<const bf16x8*>(
                cx.qbase + (size_t)(q0w + m * 16 + l16) * D_MODEL + kh * 32 + quad * 8);

    f32x4 o[2][4];
    f32x4 c_l[2];     // row-sum accumulator (l = P @ ones)
#pragma unroll
    for (int m = 0; m < 2; ++m) {
#pragma unroll
        for (int i = 0; i < 4; ++i) o[m][i] = (f32x4){0.f, 0.f, 0.f, 0.f};
        c_l[m] = (f32x4){0.f, 0.f, 0.f, 0.f};
    }
    float m2[2][4];   // running max, log2 domain
#pragma unroll
    for (int m = 0; m < 2; ++m)
#pragma unroll
        for (int r = 0; r < 4; ++r) m2[m][r] = 0.f;

    const int kv_hi = q0w + 32;   // per-wave causal bound

    for (int k0 = 0; k0 < kv_hi; k0 += 64) {
        // ---- K fragments (single buffer; regs freed after QK^T) ----
        bf16x8 kf[8];
#pragma unroll
        for (int t = 0; t < 4; ++t) {
            const unsigned short* krow = cx.kbase + (size_t)(k0 + t * 16 + l16) * kvs;
            kf[2 * t]     = *reinterpret_cast<const bf16x8*>(krow + quad * 8);
            kf[2 * t + 1] = *reinterpret_cast<const bf16x8*>(krow + 32 + quad * 8);
        }

        f32x4 sc[2][4];
        __builtin_amdgcn_s_setprio(1);
#pragma unroll
        for (int t = 0; t < 4; ++t) {
#pragma unroll
            for (int m = 0; m < 2; ++m) {
                f32x4 c = (f32x4){0.f, 0.f, 0.f, 0.f};
                c = MFMA16(aq[m][0], kf[2 * t], c);
                c = MFMA16(aq[m][1], kf[2 * t + 1], c);
                sc[m][t] = c;
            }
        }
        __builtin_amdgcn_s_setprio(0);

        // ---- V fragments issued early (cover latency under softmax) ----
        bf16x8 vf[8];
#pragma unroll
        for (int nt = 0; nt < 4; ++nt) {
            const unsigned short* vrow =
                cx.vtbase + (size_t)(nt * 16 + l16) * S_LEN + k0 + quad * 8;
            vf[2 * nt]     = *reinterpret_cast<const bf16x8*>(vrow);
            vf[2 * nt + 1] = *reinterpret_cast<const bf16x8*>(vrow + 32);
        }

        const bool full = (k0 + 63 <= q0w);
        float pm[2][4];
        float dif = -3.0e38f;
#pragma unroll
        for (int m = 0; m < 2; ++m) {
#pragma unroll
            for (int r = 0; r < 4; ++r) {
                const int qi = q0w + m * 16 + quad * 4 + r;
                float s[4];
#pragma unroll
                for (int t = 0; t < 4; ++t) {
                    s[t] = sc[m][t][r] * SM_C;
                    if (!full && (k0 + t * 16 + l16 > qi)) s[t] = -1.0e30f;
                    sc[m][t][r] = s[t];
                }
                const float p = fmaxf(fmaxf(s[0], s[1]), fmaxf(s[2], s[3]));
                pm[m][r] = p;
                dif = fmaxf(dif, p - m2[m][r]);
            }
        }
        if (__any(dif > SM_THR)) {
#pragma unroll
            for (int m = 0; m < 2; ++m) {
#pragma unroll
                for (int r = 0; r < 4; ++r) {
                    float mt = pm[m][r];
#pragma unroll
                    for (int off = 1; off < 16; off <<= 1)
                        mt = fmaxf(mt, __shfl_xor(mt, off, 64));
                    const float mn = fmaxf(m2[m][r], mt);
                    const float al = fexp2(m2[m][r] - mn);
                    m2[m][r] = mn;
#pragma unroll
                    for (int nt = 0; nt < 4; ++nt) o[m][nt][r] *= al;
                    c_l[m][r] *= al;
                }
            }
        }
        // pass 2: p = 2^(s - m2), write P tile
#pragma unroll
        for (int m = 0; m < 2; ++m) {
#pragma unroll
            for (int r = 0; r < 4; ++r) {
                const float mb = m2[m][r];
#pragma unroll
                for (int t = 0; t < 4; ++t) {
                    const float pv = fexp2(sc[m][t][r] - mb);
                    cx.lpw[m * 16 + quad * 4 + r][t * 16 + l16] = f2bf(pv);
                }
            }
        }
        asm volatile("" ::: "memory");
        bf16x8 ap[2][2];
#pragma unroll
        for (int m = 0; m < 2; ++m)
#pragma unroll
            for (int kh = 0; kh < 2; ++kh)
                ap[m][kh] = *reinterpret_cast<const bf16x8*>(
                    &cx.lpw[m * 16 + l16][kh * 32 + quad * 8]);
        __builtin_amdgcn_s_setprio(1);
#pragma unroll
        for (int nt = 0; nt < 4; ++nt)
#pragma unroll
            for (int m = 0; m < 2; ++m) {
                o[m][nt] = MFMA16(ap[m][0], vf[2 * nt], o[m][nt]);
                o[m][nt] = MFMA16(ap[m][1], vf[2 * nt + 1], o[m][nt]);
            }
#pragma unroll
        for (int m = 0; m < 2; ++m) {
            c_l[m] = MFMA16(ap[m][0], ones, c_l[m]);
            c_l[m] = MFMA16(ap[m][1], ones, c_l[m]);
        }
        __builtin_amdgcn_s_setprio(0);
    }

#pragma unroll
    for (int m = 0; m < 2; ++m)
#pragma unroll
        for (int r = 0; r < 4; ++r) {
            const float inv_l = 1.0f / c_l[m][r];
            unsigned short* orow = cx.obase + (size_t)(q0w + m * 16 + quad * 4 + r) * D_MODEL;
#pragma unroll
            for (int nt = 0; nt < 4; ++nt)
                orow[nt * 16 + l16] = f2bf(o[m][nt][r] * inv_l);
        }
}

__global__ __launch_bounds__(256) void attn_kernel7(const unsigned short* __restrict__ Q,
                                                    const unsigned short* __restrict__ Kb,
                                                    const unsigned short* __restrict__ Vt,
                                                    unsigned short* __restrict__ O, int kvs) {
    __shared__ unsigned short lp[4][32][72];   // per-wave P (32 q x 64 k), padded

    const int wave = threadIdx.x >> 6;
    const int lane = threadIdx.x & 63;

    // Grid 1024 = 16 q-tiers x 64 (b,h). Tier 0 = heaviest q-tile (qt=15),
    // dispatched first so the longest-running blocks start earliest.
    const int bid  = blockIdx.x;
    const int qt   = 15 - (bid >> 6);
    const int bh   = bid & 63;
    const int h    = bh & (NHEAD - 1);
    const int b    = bh >> 5;
    const int kvh  = h >> 2;

    AttnCtx cx;
    cx.qbase  = Q + (size_t)b * S_LEN * D_MODEL + h * HEAD_DIM;
    cx.kbase  = Kb + (size_t)b * S_LEN * kvs + kvh * HEAD_DIM;
    cx.vtbase = Vt + ((size_t)b * KVW + kvh * HEAD_DIM) * S_LEN;
    cx.obase  = O + (size_t)b * S_LEN * D_MODEL + h * HEAD_DIM;
    cx.kvs    = kvs;
    cx.l16    = lane & 15;
    cx.quad   = lane >> 4;
    cx.lpw    = lp[wave];

    attn_qtile(cx, qt * 128 + wave * 32);
}

// ---------------------------------------------------------------------------
// Legacy direct-load GEMM + attention (fallback path only).
// ---------------------------------------------------------------------------
__global__ __launch_bounds__(256) void gemm_bt(const void* __restrict__ Ap,
                                               const void* __restrict__ Wp,
                                               void* __restrict__ Cp, int N,
                                               const unsigned short* __restrict__ hdet,
                                               int a_input, int rope, int finalout) {
    const bool isf32 = detect_f32_block(hdet);
    const bool af32 = isf32 && (a_input != 0);
    const bool wf32 = isf32;
    const bool of32 = isf32 && (finalout != 0);

    const int wave = threadIdx.x >> 6;
    const int lane = threadIdx.x & 63;
    const int l16  = lane & 15;
    const int quad = lane >> 4;
    const int m0 = blockIdx.x * 64 + wave * 16;
    const int n0 = blockIdx.y * 64;

    f32x4 acc[4];
#pragma unroll
    for (int i = 0; i < 4; ++i) acc[i] = (f32x4){0.f, 0.f, 0.f, 0.f};

    const size_t aoff = (size_t)(m0 + l16) * D_MODEL + quad * 8;
    size_t woff[4];
#pragma unroll
    for (int nt = 0; nt < 4; ++nt)
        woff[nt] = (size_t)(n0 + nt * 16 + l16) * D_MODEL + quad * 8;

    for (int k0 = 0; k0 < D_MODEL; k0 += 32) {
        bf16x8 a = load_frag(af32, Ap, aoff + k0);
#pragma unroll
        for (int nt = 0; nt < 4; ++nt) {
            bf16x8 b = load_frag(wf32, Wp, woff[nt] + k0);
            acc[nt] = MFMA16(a, b, acc[nt]);
        }
    }

#pragma unroll
    for (int r = 0; r < 4; ++r) {
        const int m = m0 + quad * 4 + r;
        float vals[4];
#pragma unroll
        for (int nt = 0; nt < 4; ++nt) vals[nt] = acc[nt][r];
        float outv[4];
        if (rope) {
            rope4(vals, outv, m, l16);
        } else {
#pragma unroll
            for (int nt = 0; nt < 4; ++nt) outv[nt] = vals[nt];
        }
        const size_t crow = (size_t)m * N + n0;
        if (of32) {
            float* cp = (float*)Cp + crow;
#pragma unroll
            for (int nt = 0; nt < 4; ++nt) cp[nt * 16 + l16] = outv[nt];
        } else {
            unsigned short* cp = (unsigned short*)Cp + crow;
#pragma unroll
            for (int nt = 0; nt < 4; ++nt) cp[nt * 16 + l16] = f2bf(outv[nt]);
        }
    }
}

__global__ __launch_bounds__(256) void attn_kernel(const unsigned short* __restrict__ Q,
                                                   const unsigned short* __restrict__ Kb,
                                                   const unsigned short* __restrict__ Vb,
                                                   unsigned short* __restrict__ O, int kvs) {
    __shared__ unsigned short lp[4][16][32];

    const int wave = threadIdx.x >> 6;
    const int lane = threadIdx.x & 63;
    const int l16  = lane & 15;
    const int quad = lane >> 4;

    const int bid = blockIdx.x;
    const int qb  = bid & 31;
    const int h   = (bid >> 5) & 31;
    const int b   = bid >> 10;
    const int kvh = h >> 2;
    const int q0  = qb * 64 + wave * 16;

    const unsigned short* qbase = Q + (size_t)b * S_LEN * D_MODEL + h * HEAD_DIM;
    const unsigned short* kbase = Kb + (size_t)b * S_LEN * kvs + kvh * HEAD_DIM;
    const unsigned short* vbase = Vb + (size_t)b * S_LEN * kvs + kvh * HEAD_DIM;

    bf16x8 aq0 = *reinterpret_cast<const bf16x8*>(qbase + (size_t)(q0 + l16) * D_MODEL + quad * 8);
    bf16x8 aq1 = *reinterpret_cast<const bf16x8*>(qbase + (size_t)(q0 + l16) * D_MODEL + 32 + quad * 8);

    f32x4 o[4];
#pragma unroll
    for (int i = 0; i < 4; ++i) o[i] = (f32x4){0.f, 0.f, 0.f, 0.f};
    float mrow[4], lrow[4];
#pragma unroll
    for (int r = 0; r < 4; ++r) { mrow[r] = -3.0e38f; lrow[r] = 0.f; }

    const int kv_hi = qb * 64 + 64;
    for (int k0 = 0; k0 < kv_hi; k0 += 32) {
        f32x4 sc[2];
#pragma unroll
        for (int t = 0; t < 2; ++t) {
            const unsigned short* krow = kbase + (size_t)(k0 + t * 16 + l16) * kvs;
            bf16x8 b0 = *reinterpret_cast<const bf16x8*>(krow + quad * 8);
            bf16x8 b1 = *reinterpret_cast<const bf16x8*>(krow + 32 + quad * 8);
            f32x4 c = (f32x4){0.f, 0.f, 0.f, 0.f};
            c = MFMA16(aq0, b0, c);
            c = MFMA16(aq1, b1, c);
            sc[t] = c;
        }

        float alpha[4], p0v[4], p1v[4];
#pragma unroll
        for (int r = 0; r < 4; ++r) {
            const int qi = q0 + quad * 4 + r;
            float s0 = sc[0][r] * 0.125f;
            float s1 = sc[1][r] * 0.125f;
            if (k0 + l16 > qi)       s0 = -1.0e30f;
            if (k0 + 16 + l16 > qi)  s1 = -1.0e30f;
            float mt = fmaxf(s0, s1);
#pragma unroll
            for (int off = 1; off < 16; off <<= 1) mt = fmaxf(mt, __shfl_xor(mt, off, 64));
            const float mn = fmaxf(mrow[r], mt);
            const float al = __expf(mrow[r] - mn);
            const float p0 = __expf(s0 - mn);
            const float p1 = __expf(s1 - mn);
            float rs = p0 + p1;
#pragma unroll
            for (int off = 1; off < 16; off <<= 1) rs += __shfl_xor(rs, off, 64);
            lrow[r] = lrow[r] * al + rs;
            mrow[r] = mn;
            alpha[r] = al;
            p0v[r] = p0; p1v[r] = p1;
        }
#pragma unroll
        for (int nt = 0; nt < 4; ++nt)
#pragma unroll
            for (int r = 0; r < 4; ++r) o[nt][r] *= alpha[r];

        __syncthreads();
#pragma unroll
        for (int r = 0; r < 4; ++r) {
            lp[wave][quad * 4 + r][l16]      = f2bf(p0v[r]);
            lp[wave][quad * 4 + r][16 + l16] = f2bf(p1v[r]);
        }
        __syncthreads();
        bf16x8 ap = *reinterpret_cast<const bf16x8*>(&lp[wave][l16][quad * 8]);

#pragma unroll
        for (int nt = 0; nt < 4; ++nt) {
            const unsigned short* vcol = vbase + nt * 16 + l16 + (size_t)(k0 + quad * 8) * kvs;
            bf16x8 bv;
#pragma unroll
            for (int j = 0; j < 8; ++j) bv[j] = (short)vcol[(size_t)j * kvs];
            o[nt] = MFMA16(ap, bv, o[nt]);
        }
    }

    unsigned short* obase = O + (size_t)b * S_LEN * D_MODEL + h * HEAD_DIM;
#pragma unroll
    for (int r = 0; r < 4; ++r) {
        const float inv_l = 1.0f / lrow[r];
        unsigned short* orow = obase + (size_t)(q0 + quad * 4 + r) * D_MODEL;
#pragma unroll
        for (int nt = 0; nt < 4; ++nt)
            orow[nt * 16 + l16] = f2bf(o[nt][r] * inv_l);
    }
}

extern "C" void kernel_launch(void* const* d_in, const int* in_sizes, int n_in,
                              void* d_out, int out_size, void* d_ws, size_t ws_size,
                              hipStream_t stream) {
    const void* hidden = d_in[0];
    const void* Wq = d_in[1];
    const void* Wk = d_in[2];
    const void* Wv = d_in[3];
    const void* Wo = d_in[4];
    // d_in[5] = attention_mask: pure causal -1e9 -> implemented directly.

    char* ws = (char*)d_ws;
    dim3 blk(256);

    // kv 8MB + abuf 16MB + hbuf 16MB + wq 8MB + wkv 4MB + wo 8MB + vt 4MB + tab 512KB
    const size_t NEED = 1024 + ((size_t)64 << 20) + (512u << 10);
    if (ws_size >= NEED) {
        unsigned short* kvbuf = (unsigned short*)(ws + 1024);      // [4096,1024]: K cols 0-511, V cols 512-1023
        unsigned short* abuf  = kvbuf + (size_t)4096 * 1024;       // [4096,2048]
        unsigned short* hbuf  = abuf + (size_t)4096 * 2048;        // hidden bf16
        unsigned short* wqb   = hbuf + (size_t)4096 * 2048;        // [2048,2048]  } contiguous =
        unsigned short* wkvb  = wqb + (size_t)2048 * 2048;         // [1024,2048]  } Wqkv [3072,2048]
        unsigned short* wob   = wkvb + (size_t)1024 * 2048;        // [2048,2048]
        unsigned short* vtbuf = wob + (size_t)2048 * 2048;         // [2,512,2048] V^T
        float2* ropetab       = (float2*)(vtbuf + (size_t)2 * 512 * 2048);  // [2048][32]
        unsigned short* qbuf  = (unsigned short*)d_out;            // Q bf16 lives in d_out

        cvt_all<<<dim3(2048), blk, 0, stream>>>(hidden, Wq, Wk, Wv, Wo,
                                                hbuf, wqb, wkvb, wob, ropetab);

        gemm_qkv_lds<<<dim3(32, 24), blk, 0, stream>>>(hbuf, wqb, qbuf, kvbuf, ropetab);
        transpose_v<<<dim3(512), blk, 0, stream>>>(kvbuf + 512, vtbuf);
        attn_kernel7<<<dim3(2 * NHEAD * (S_LEN / 128)), blk, 0, stream>>>(qbuf, kvbuf, vtbuf, abuf, 1024);
        gemm_bt_lds<<<dim3(32, 16), blk, 0, stream>>>(abuf, wob, d_out, 2048,
                                                      (const unsigned short*)hidden, 0, 1);
    } else {
        // legacy 24MB path
        unsigned short* kbuf = (unsigned short*)(ws + 1024);
        unsigned short* vbuf = (unsigned short*)(ws + 1024 + (4u << 20));
        unsigned short* abuf = (unsigned short*)(ws + 1024 + (8u << 20));
        unsigned short* qbuf = (unsigned short*)d_out;
        const unsigned short* hdet = (const unsigned short*)hidden;
        gemm_bt<<<dim3(M_ROWS / 64, D_MODEL / 64), blk, 0, stream>>>(hidden, Wq, qbuf, D_MODEL, hdet, 1, 1, 0);
        gemm_bt<<<dim3(M_ROWS / 64, (NKVH * HEAD_DIM) / 64), blk, 0, stream>>>(hidden, Wk, kbuf, NKVH * HEAD_DIM, hdet, 1, 1, 0);
        gemm_bt<<<dim3(M_ROWS / 64, (NKVH * HEAD_DIM) / 64), blk, 0, stream>>>(hidden, Wv, vbuf, NKVH * HEAD_DIM, hdet, 1, 0, 0);
        attn_kernel<<<dim3(2 * NHEAD * (S_LEN / 64)), blk, 0, stream>>>(qbuf, kbuf, vbuf, abuf, 512);
        gemm_bt<<<dim3(M_ROWS / 64, D_MODEL / 64), blk, 0, stream>>>(abuf, Wo, d_out, D_MODEL, hdet, 0, 0, 1);
    }
}

// Round 10
// 423.785 us; speedup vs baseline: 2.6395x; 1.0056x over previous
//
#include <hip/hip_runtime.h>

// FlashAttentionWrapper: B=2, S=2048, D=2048, NH=32, HD=64, NKV=8, NREP=4,
// causal, RoPE theta=1e4. Input dtype (bf16/f32) self-detected per block.
// New-path workspace (64MB+1KB+512KB):
//   [1KB pad][kvbuf 4096x1024 8MB][abuf 4096x2048 16MB]
//   [hbuf 16MB][wqb 8MB][wkvb 4MB][wob 8MB][vtbuf 2x512x2048 4MB]
//   [ropetab 2048x32 float2 512KB]
// wqb+wkvb are CONTIGUOUS => one [3072,2048] QKV weight matrix (fused GEMM).
// Q-projection result lives in d_out (dead before O-proj overwrites it).
// Fallback path (ws too small): original direct-load kernels, 24MB+1KB.
//
// Round-5 lesson: hand-written v_cvt_pk_bf16_f32 asm mis-packed (absmax 3.6).
// Round-8 lesson: forced launch_bounds occupancy => scratch spill (32x traffic).
// Round-9 lesson: attn occupancy 11->21% gave 0 speedup — attn is NOT
// TLP-starved; budget math showed GEMMs at only ~400 TF (227us).
// Round-10: GEMMs get T3 "minimum 2-phase" double-buffered LDS — issue
// next-tile global_load_lds BEFORE compute, single barrier per K-step whose
// vmcnt(0) drain is overlapped by the MFMA phase (current code drained with
// zero compute in flight, exposing full global latency every K-step).

#define S_LEN 2048
#define D_MODEL 2048
#define NHEAD 32
#define HEAD_DIM 64
#define NKVH 8
#define M_ROWS 4096   // B*S
#define KVW (NKVH * HEAD_DIM)   // 512

typedef __attribute__((ext_vector_type(4))) float f32x4;
typedef __attribute__((ext_vector_type(8))) short bf16x8;

#define MFMA16(a, b, c) __builtin_amdgcn_mfma_f32_16x16x32_bf16((a), (b), (c), 0, 0, 0)

// async global->LDS, 16B per lane; LDS dest is wave-uniform base + lane*16
#define GLOAD_LDS16(g, l)                                                     \
    __builtin_amdgcn_global_load_lds(                                         \
        (const __attribute__((address_space(1))) void*)(g),                   \
        (__attribute__((address_space(3))) void*)(l), 16, 0, 0)

// f32 -> bf16 RNE via native cast (compiler emits the HW convert).
static __device__ __forceinline__ unsigned short f2bf(float f) {
    union { __bf16 b; unsigned short u; } v;
    v.b = (__bf16)f;
    return v.u;
}

static __device__ __forceinline__ float fexp2(float x) {
#if __has_builtin(__builtin_amdgcn_exp2f)
    return __builtin_amdgcn_exp2f(x);
#else
    return exp2f(x);
#endif
}

// XCD-chunked swizzle of a 2D grid (requires gridDim.x*gridDim.y % 8 == 0).
static __device__ __forceinline__ void xcd_swz(int& bx, int& by) {
    const int gx = gridDim.x;
    const int nwg = gx * gridDim.y;
    int lin = blockIdx.y * gx + blockIdx.x;
    lin = (lin & 7) * (nwg >> 3) + (lin >> 3);
    bx = lin % gx;
    by = lin / gx;
}

// ---------------------------------------------------------------------------
// Per-block dtype self-detection: f32 data read as uint16 shows impossible
// bf16 exponents at even indices. Called uniformly by all 256 threads.
// ---------------------------------------------------------------------------
static __device__ bool detect_f32_block(const unsigned short* __restrict__ h) {
    __shared__ int dcnt;
    if (threadIdx.x == 0) dcnt = 0;
    __syncthreads();
    const unsigned short v = h[2 * (threadIdx.x & 255)];
    const int e = (v >> 7) & 0xFF;
    if (threadIdx.x < 256 && e >= 0x8D) atomicAdd(&dcnt, 1);
    __syncthreads();
    return dcnt >= 8;
}

static __device__ __forceinline__ bf16x8 load_frag(bool f32p, const void* p, size_t off) {
    if (f32p) {
        const float* fp = (const float*)p + off;
        f32x4 x = *reinterpret_cast<const f32x4*>(fp);
        f32x4 y = *reinterpret_cast<const f32x4*>(fp + 4);
        bf16x8 r;
        r[0] = (short)f2bf(x[0]); r[1] = (short)f2bf(x[1]);
        r[2] = (short)f2bf(x[2]); r[3] = (short)f2bf(x[3]);
        r[4] = (short)f2bf(y[0]); r[5] = (short)f2bf(y[1]);
        r[6] = (short)f2bf(y[2]); r[7] = (short)f2bf(y[3]);
        return r;
    }
    return *reinterpret_cast<const bf16x8*>((const unsigned short*)p + off);
}

// ---------------------------------------------------------------------------
// Fused one-time f32->bf16 conversion (or bf16 copy) of all 5 operands,
// plus the RoPE cos/sin table (tab[s*32+dd] = cos/sin of s*10000^(-dd/32)).
// ---------------------------------------------------------------------------
__global__ __launch_bounds__(256) void cvt_all(const void* __restrict__ h,
                                               const void* __restrict__ wq,
                                               const void* __restrict__ wk,
                                               const void* __restrict__ wv,
                                               const void* __restrict__ wo,
                                               unsigned short* __restrict__ hbuf,
                                               unsigned short* __restrict__ wqb,
                                               unsigned short* __restrict__ wkvb,
                                               unsigned short* __restrict__ wob,
                                               float2* __restrict__ ropetab) {
    const bool f32p = detect_f32_block((const unsigned short*)h);
    const int e0 = 1048576;            // hidden 4096x2048
    const int e1 = e0 + 524288;        // Wq 2048x2048
    const int e2 = e1 + 131072;        // Wk 512x2048
    const int e3 = e2 + 131072;        // Wv 512x2048
    const int e4 = e3 + 524288;        // Wo 2048x2048
    const int e5 = e4 + 8192;          // rope table 2048x32 (8 entries/unit)
    int i = blockIdx.x * 256 + threadIdx.x;
    const int stride = gridDim.x * 256;
    for (; i < e5; i += stride) {
        if (i >= e4) {
            const int base = (i - e4) * 8;
#pragma unroll
            for (int j = 0; j < 8; ++j) {
                const int idx = base + j;
                const int s = idx >> 5, dd = idx & 31;
                const float inv = exp2f(-(float)dd * 0.4152410118609203f);
                const float th = (float)s * inv;
                float sn, cs;
                sincosf(th, &sn, &cs);
                ropetab[idx] = make_float2(cs, sn);
            }
            continue;
        }
        const void* s;
        unsigned short* d;
        size_t off;
        if (i < e0)      { s = h;  d = hbuf; off = (size_t)i; }
        else if (i < e1) { s = wq; d = wqb;  off = (size_t)(i - e0); }
        else if (i < e2) { s = wk; d = wkvb; off = (size_t)(i - e1); }
        else if (i < e3) { s = wv; d = wkvb + (size_t)512 * 2048; off = (size_t)(i - e2); }
        else             { s = wo; d = wob;  off = (size_t)(i - e3); }
        bf16x8 v = load_frag(f32p, s, off * 8);
        *reinterpret_cast<bf16x8*>(d + off * 8) = v;
    }
}

// ---------------------------------------------------------------------------
// RoPE epilogue helpers.
// ---------------------------------------------------------------------------
static __device__ __forceinline__ void rope4_tab(const float2* __restrict__ tab,
                                                 const float (&vals)[4], float (&outv)[4],
                                                 int m, int l16) {
    const int s = m & (S_LEN - 1);
#pragma unroll
    for (int nt = 0; nt < 4; ++nt) {
        const int d = nt * 16 + l16;
        const float2 cs = tab[s * 32 + (d & 31)];
        const float part = vals[nt ^ 2];
        const float rot = (nt < 2) ? -part : part;  // d<32: -x2 ; d>=32: +x1
        outv[nt] = vals[nt] * cs.x + rot * cs.y;
    }
}

static __device__ __forceinline__ void rope4(const float (&vals)[4], float (&outv)[4],
                                             int m, int l16) {
    const float sf = (float)(m & (S_LEN - 1));
#pragma unroll
    for (int nt = 0; nt < 4; ++nt) {
        const int d = nt * 16 + l16;
        const float inv = exp2f(-(float)(d & 31) * 0.4152410118609203f);
        const float th = sf * inv;
        float sn, cs;
        sincosf(th, &sn, &cs);
        const float part = vals[nt ^ 2];
        const float rot = (nt < 2) ? -part : part;
        outv[nt] = vals[nt] * cs + rot * sn;
    }
}

// ---------------------------------------------------------------------------
// 2-phase double-buffered GEMM core (T3 minimum recipe):
//   prologue: STAGE(buf0, k=0); barrier (drains);
//   loop: STAGE(buf^1, k+32) -> ds_read+16 MFMA from buf -> barrier -> flip.
// The barrier's implicit vmcnt(0) drain is overlapped by the MFMA phase.
// Safety: staged buffer was fully read before the PREVIOUS barrier.
// ---------------------------------------------------------------------------
#define GEMM_STAGE(BB, KK)                                                    \
    {                                                                         \
        _Pragma("unroll")                                                     \
        for (int i_ = 0; i_ < 2; ++i_) {                                      \
            const int c_ = wave * 2 + i_;                                     \
            GLOAD_LDS16(ag[i_] + (KK), &lds_a[BB][c_ * 512]);                 \
            GLOAD_LDS16(wg[i_] + (KK), &lds_b[BB][c_ * 512]);                 \
        }                                                                     \
    }

#define GEMM_MAINLOOP()                                                       \
    GEMM_STAGE(0, 0);                                                         \
    __syncthreads();                                                          \
    {                                                                         \
        int cur = 0;                                                          \
        for (int k0 = 0; k0 < D_MODEL; k0 += 32) {                            \
            if (k0 + 32 < D_MODEL) GEMM_STAGE(cur ^ 1, k0 + 32);              \
            bf16x8 af[4], bfm[4];                                             \
            _Pragma("unroll")                                                 \
            for (int t = 0; t < 4; ++t) {                                     \
                af[t]  = *reinterpret_cast<const bf16x8*>(                    \
                    &lds_a[cur][(wm * 64 + t * 16 + l16) * 32 + quad * 8]);   \
                bfm[t] = *reinterpret_cast<const bf16x8*>(                    \
                    &lds_b[cur][(wn * 64 + t * 16 + l16) * 32 + quad * 8]);   \
            }                                                                 \
            _Pragma("unroll")                                                 \
            for (int mt = 0; mt < 4; ++mt)                                    \
                _Pragma("unroll")                                             \
                for (int nt = 0; nt < 4; ++nt)                                \
                    acc[mt][nt] = MFMA16(af[mt], bfm[nt], acc[mt][nt]);       \
            __syncthreads();                                                  \
            cur ^= 1;                                                         \
        }                                                                     \
    }

// ---------------------------------------------------------------------------
// Fused QKV GEMM: A[4096,2048] @ Wqkv[3072,2048]^T, all bf16. 128x128 tile,
// BK=32, 4 waves 2x2, 2-phase dbuf staging, XCD swizzle. Epilogue routes each
// wave's head-aligned 64-col span: cols<2048 -> Q (RoPE); 2048..2559 -> K
// half of kvbuf (RoPE); >=2560 -> V half (no RoPE). RoPE via table.
// ---------------------------------------------------------------------------
__global__ __launch_bounds__(256) void gemm_qkv_lds(const unsigned short* __restrict__ A,
                                                    const unsigned short* __restrict__ W,
                                                    unsigned short* __restrict__ Qo,
                                                    unsigned short* __restrict__ KVo,
                                                    const float2* __restrict__ ropetab) {
    __shared__ unsigned short lds_a[2][128 * 32];   // 2 x 8KB
    __shared__ unsigned short lds_b[2][128 * 32];   // 2 x 8KB

    const int wave = threadIdx.x >> 6;
    const int lane = threadIdx.x & 63;
    const int l16  = lane & 15;
    const int quad = lane >> 4;
    const int wm   = wave >> 1;
    const int wn   = wave & 1;

    int bx, by;
    xcd_swz(bx, by);
    const int m0 = bx * 128;
    const int n0 = by * 128;

    const int srow = lane >> 2;
    const int scol = (lane & 3) * 8;
    const unsigned short* ag[2];
    const unsigned short* wg[2];
#pragma unroll
    for (int i = 0; i < 2; ++i) {
        const int c = wave * 2 + i;
        ag[i] = A + (size_t)(m0 + c * 16 + srow) * D_MODEL + scol;
        wg[i] = W + (size_t)(n0 + c * 16 + srow) * D_MODEL + scol;
    }

    f32x4 acc[4][4];
#pragma unroll
    for (int i = 0; i < 4; ++i)
#pragma unroll
        for (int j = 0; j < 4; ++j) acc[i][j] = (f32x4){0.f, 0.f, 0.f, 0.f};

    GEMM_MAINLOOP();

    const int ncol0 = n0 + wn * 64;                 // wave-uniform, head-aligned
    const bool do_rope = (ncol0 < 2048 + KVW);      // Q and K regions
    unsigned short* dst;
    int cstride, c0;
    if (ncol0 < 2048) { dst = Qo;  cstride = 2048; c0 = ncol0; }
    else              { dst = KVo; cstride = 1024; c0 = ncol0 - 2048; }

#pragma unroll
    for (int mt = 0; mt < 4; ++mt) {
#pragma unroll
        for (int r = 0; r < 4; ++r) {
            const int m = m0 + wm * 64 + mt * 16 + quad * 4 + r;
            float vals[4];
#pragma unroll
            for (int nt = 0; nt < 4; ++nt) vals[nt] = acc[mt][nt][r];
            float outv[4];
            if (do_rope) {
                rope4_tab(ropetab, vals, outv, m, l16);
            } else {
#pragma unroll
                for (int nt = 0; nt < 4; ++nt) outv[nt] = vals[nt];
            }
            unsigned short* cp = dst + (size_t)m * cstride + c0;
#pragma unroll
            for (int nt = 0; nt < 4; ++nt) cp[nt * 16 + l16] = f2bf(outv[nt]);
        }
    }
}

// ---------------------------------------------------------------------------
// O-projection GEMM: C[M,N] = A[M,2048] @ W[N,2048]^T, bf16, 2-phase dbuf,
// XCD swizzle. finalout + f32 input -> f32 output (dtype via self-detect).
// ---------------------------------------------------------------------------
__global__ __launch_bounds__(256) void gemm_bt_lds(const unsigned short* __restrict__ A,
                                                   const unsigned short* __restrict__ W,
                                                   void* __restrict__ Cp, int N,
                                                   const unsigned short* __restrict__ hdet,
                                                   int rope, int finalout) {
    __shared__ unsigned short lds_a[2][128 * 32];
    __shared__ unsigned short lds_b[2][128 * 32];

    bool of32 = false;
    if (finalout) of32 = detect_f32_block(hdet);

    const int wave = threadIdx.x >> 6;
    const int lane = threadIdx.x & 63;
    const int l16  = lane & 15;
    const int quad = lane >> 4;
    const int wm   = wave >> 1;
    const int wn   = wave & 1;

    int bx, by;
    xcd_swz(bx, by);
    const int m0 = bx * 128;
    const int n0 = by * 128;

    const int srow = lane >> 2;
    const int scol = (lane & 3) * 8;
    const unsigned short* ag[2];
    const unsigned short* wg[2];
#pragma unroll
    for (int i = 0; i < 2; ++i) {
        const int c = wave * 2 + i;
        ag[i] = A + (size_t)(m0 + c * 16 + srow) * D_MODEL + scol;
        wg[i] = W + (size_t)(n0 + c * 16 + srow) * D_MODEL + scol;
    }

    f32x4 acc[4][4];
#pragma unroll
    for (int i = 0; i < 4; ++i)
#pragma unroll
        for (int j = 0; j < 4; ++j) acc[i][j] = (f32x4){0.f, 0.f, 0.f, 0.f};

    GEMM_MAINLOOP();

    const bool do_rope = (rope != 0);
    const int ncol0 = n0 + wn * 64;

#pragma unroll
    for (int mt = 0; mt < 4; ++mt) {
#pragma unroll
        for (int r = 0; r < 4; ++r) {
            const int m = m0 + wm * 64 + mt * 16 + quad * 4 + r;
            float vals[4];
#pragma unroll
            for (int nt = 0; nt < 4; ++nt) vals[nt] = acc[mt][nt][r];
            float outv[4];
            if (do_rope) {
                rope4(vals, outv, m, l16);
            } else {
#pragma unroll
                for (int nt = 0; nt < 4; ++nt) outv[nt] = vals[nt];
            }
            const size_t crow = (size_t)m * N + ncol0;
            if (of32) {
                float* cp = (float*)Cp + crow;
#pragma unroll
                for (int nt = 0; nt < 4; ++nt) cp[nt * 16 + l16] = outv[nt];
            } else {
                unsigned short* cp = (unsigned short*)Cp + crow;
#pragma unroll
                for (int nt = 0; nt < 4; ++nt) cp[nt * 16 + l16] = f2bf(outv[nt]);
            }
        }
    }
}

// ---------------------------------------------------------------------------
// V transpose: Vsrc = kvbuf V-half [B*S rows, stride 1024] cols 0..511
//   -> Vt[b][c][s] ([B][512][S]).  64x64 LDS tiles, fully coalesced.
// ---------------------------------------------------------------------------
__global__ __launch_bounds__(256) void transpose_v(const unsigned short* __restrict__ Vsrc,
                                                   unsigned short* __restrict__ Vt) {
    __shared__ unsigned short t[64][72];
    const int bid = blockIdx.x;
    const int ct = bid & 7;
    const int st = (bid >> 3) & 31;
    const int b  = bid >> 8;
    const unsigned short* src = Vsrc + ((size_t)b * S_LEN + st * 64) * 1024 + ct * 64;
    unsigned short* dst = Vt + ((size_t)b * KVW + ct * 64) * S_LEN + st * 64;
    const int r0 = threadIdx.x >> 3;
    const int c0 = (threadIdx.x & 7) * 8;
#pragma unroll
    for (int h = 0; h < 2; ++h) {
        bf16x8 v = *reinterpret_cast<const bf16x8*>(src + (size_t)(r0 + h * 32) * 1024 + c0);
        *reinterpret_cast<bf16x8*>(&t[r0 + h * 32][c0]) = v;
    }
    __syncthreads();
#pragma unroll
    for (int h = 0; h < 2; ++h) {
        const int cr = r0 + h * 32;
        bf16x8 v;
#pragma unroll
        for (int j = 0; j < 8; ++j) v[j] = (short)t[c0 + j][cr];
        *reinterpret_cast<bf16x8*>(dst + (size_t)cr * S_LEN + c0) = v;
    }
}

// ---------------------------------------------------------------------------
// Flash attention v7 (round-9 verified: VGPR 128, no spill, 139us):
// single-buffered K (regs reused for vf), deferred max THR=8, row-sum via
// MFMA, vf-early. Grid 1024, globally heavy-first.
// ---------------------------------------------------------------------------
struct AttnCtx {
    const unsigned short* qbase;
    const unsigned short* kbase;
    const unsigned short* vtbase;
    unsigned short* obase;
    int kvs;
    int l16, quad;
    unsigned short (*lpw)[72];   // [32][72] per-wave slice
};

#define SM_C 0.18033688011112042f   // 0.125 * log2(e)
#define SM_THR 8.0f

static __device__ __forceinline__ void attn_qtile(const AttnCtx& cx, int q0w) {
    const int l16 = cx.l16, quad = cx.quad;
    const int kvs = cx.kvs;

    bf16x8 ones;
#pragma unroll
    for (int j = 0; j < 8; ++j) ones[j] = (short)0x3F80;   // bf16 1.0

    bf16x8 aq[2][2];
#pragma unroll
    for (int m = 0; m < 2; ++m)
#pragma unroll
        for (int kh = 0; kh < 2; ++kh)
            aq[m][kh] = *reinterpret_cast<const bf16x8*>(
                cx.qbase + (size_t)(q0w + m * 16 + l16) * D_MODEL + kh * 32 + quad * 8);

    f32x4 o[2][4];
    f32x4 c_l[2];     // row-sum accumulator (l = P @ ones)
#pragma unroll
    for (int m = 0; m < 2; ++m) {
#pragma unroll
        for (int i = 0; i < 4; ++i) o[m][i] = (f32x4){0.f, 0.f, 0.f, 0.f};
        c_l[m] = (f32x4){0.f, 0.f, 0.f, 0.f};
    }
    float m2[2][4];   // running max, log2 domain
#pragma unroll
    for (int m = 0; m < 2; ++m)
#pragma unroll
        for (int r = 0; r < 4; ++r) m2[m][r] = 0.f;

    const int kv_hi = q0w + 32;   // per-wave causal bound

    for (int k0 = 0; k0 < kv_hi; k0 += 64) {
        // ---- K fragments (single buffer; regs freed after QK^T) ----
        bf16x8 kf[8];
#pragma unroll
        for (int t = 0; t < 4; ++t) {
            const unsigned short* krow = cx.kbase + (size_t)(k0 + t * 16 + l16) * kvs;
            kf[2 * t]     = *reinterpret_cast<const bf16x8*>(krow + quad * 8);
            kf[2 * t + 1] = *reinterpret_cast<const bf16x8*>(krow + 32 + quad * 8);
        }

        f32x4 sc[2][4];
        __builtin_amdgcn_s_setprio(1);
#pragma unroll
        for (int t = 0; t < 4; ++t) {
#pragma unroll
            for (int m = 0; m < 2; ++m) {
                f32x4 c = (f32x4){0.f, 0.f, 0.f, 0.f};
                c = MFMA16(aq[m][0], kf[2 * t], c);
                c = MFMA16(aq[m][1], kf[2 * t + 1], c);
                sc[m][t] = c;
            }
        }
        __builtin_amdgcn_s_setprio(0);

        // ---- V fragments issued early (cover latency under softmax) ----
        bf16x8 vf[8];
#pragma unroll
        for (int nt = 0; nt < 4; ++nt) {
            const unsigned short* vrow =
                cx.vtbase + (size_t)(nt * 16 + l16) * S_LEN + k0 + quad * 8;
            vf[2 * nt]     = *reinterpret_cast<const bf16x8*>(vrow);
            vf[2 * nt + 1] = *reinterpret_cast<const bf16x8*>(vrow + 32);
        }

        const bool full = (k0 + 63 <= q0w);
        float pm[2][4];
        float dif = -3.0e38f;
#pragma unroll
        for (int m = 0; m < 2; ++m) {
#pragma unroll
            for (int r = 0; r < 4; ++r) {
                const int qi = q0w + m * 16 + quad * 4 + r;
                float s[4];
#pragma unroll
                for (int t = 0; t < 4; ++t) {
                    s[t] = sc[m][t][r] * SM_C;
                    if (!full && (k0 + t * 16 + l16 > qi)) s[t] = -1.0e30f;
                    sc[m][t][r] = s[t];
                }
                const float p = fmaxf(fmaxf(s[0], s[1]), fmaxf(s[2], s[3]));
                pm[m][r] = p;
                dif = fmaxf(dif, p - m2[m][r]);
            }
        }
        if (__any(dif > SM_THR)) {
#pragma unroll
            for (int m = 0; m < 2; ++m) {
#pragma unroll
                for (int r = 0; r < 4; ++r) {
                    float mt = pm[m][r];
#pragma unroll
                    for (int off = 1; off < 16; off <<= 1)
                        mt = fmaxf(mt, __shfl_xor(mt, off, 64));
                    const float mn = fmaxf(m2[m][r], mt);
                    const float al = fexp2(m2[m][r] - mn);
                    m2[m][r] = mn;
#pragma unroll
                    for (int nt = 0; nt < 4; ++nt) o[m][nt][r] *= al;
                    c_l[m][r] *= al;
                }
            }
        }
        // pass 2: p = 2^(s - m2), write P tile
#pragma unroll
        for (int m = 0; m < 2; ++m) {
#pragma unroll
            for (int r = 0; r < 4; ++r) {
                const float mb = m2[m][r];
#pragma unroll
                for (int t = 0; t < 4; ++t) {
                    const float pv = fexp2(sc[m][t][r] - mb);
                    cx.lpw[m * 16 + quad * 4 + r][t * 16 + l16] = f2bf(pv);
                }
            }
        }
        asm volatile("" ::: "memory");
        bf16x8 ap[2][2];
#pragma unroll
        for (int m = 0; m < 2; ++m)
#pragma unroll
            for (int kh = 0; kh < 2; ++kh)
                ap[m][kh] = *reinterpret_cast<const bf16x8*>(
                    &cx.lpw[m * 16 + l16][kh * 32 + quad * 8]);
        __builtin_amdgcn_s_setprio(1);
#pragma unroll
        for (int nt = 0; nt < 4; ++nt)
#pragma unroll
            for (int m = 0; m < 2; ++m) {
                o[m][nt] = MFMA16(ap[m][0], vf[2 * nt], o[m][nt]);
                o[m][nt] = MFMA16(ap[m][1], vf[2 * nt + 1], o[m][nt]);
            }
#pragma unroll
        for (int m = 0; m < 2; ++m) {
            c_l[m] = MFMA16(ap[m][0], ones, c_l[m]);
            c_l[m] = MFMA16(ap[m][1], ones, c_l[m]);
        }
        __builtin_amdgcn_s_setprio(0);
    }

#pragma unroll
    for (int m = 0; m < 2; ++m)
#pragma unroll
        for (int r = 0; r < 4; ++r) {
            const float inv_l = 1.0f / c_l[m][r];
            unsigned short* orow = cx.obase + (size_t)(q0w + m * 16 + quad * 4 + r) * D_MODEL;
#pragma unroll
            for (int nt = 0; nt < 4; ++nt)
                orow[nt * 16 + l16] = f2bf(o[m][nt][r] * inv_l);
        }
}

__global__ __launch_bounds__(256) void attn_kernel7(const unsigned short* __restrict__ Q,
                                                    const unsigned short* __restrict__ Kb,
                                                    const unsigned short* __restrict__ Vt,
                                                    unsigned short* __restrict__ O, int kvs) {
    __shared__ unsigned short lp[4][32][72];   // per-wave P (32 q x 64 k), padded

    const int wave = threadIdx.x >> 6;
    const int lane = threadIdx.x & 63;

    const int bid  = blockIdx.x;
    const int qt   = 15 - (bid >> 6);
    const int bh   = bid & 63;
    const int h    = bh & (NHEAD - 1);
    const int b    = bh >> 5;
    const int kvh  = h >> 2;

    AttnCtx cx;
    cx.qbase  = Q + (size_t)b * S_LEN * D_MODEL + h * HEAD_DIM;
    cx.kbase  = Kb + (size_t)b * S_LEN * kvs + kvh * HEAD_DIM;
    cx.vtbase = Vt + ((size_t)b * KVW + kvh * HEAD_DIM) * S_LEN;
    cx.obase  = O + (size_t)b * S_LEN * D_MODEL + h * HEAD_DIM;
    cx.kvs    = kvs;
    cx.l16    = lane & 15;
    cx.quad   = lane >> 4;
    cx.lpw    = lp[wave];

    attn_qtile(cx, qt * 128 + wave * 32);
}

// ---------------------------------------------------------------------------
// Legacy direct-load GEMM + attention (fallback path only).
// ---------------------------------------------------------------------------
__global__ __launch_bounds__(256) void gemm_bt(const void* __restrict__ Ap,
                                               const void* __restrict__ Wp,
                                               void* __restrict__ Cp, int N,
                                               const unsigned short* __restrict__ hdet,
                                               int a_input, int rope, int finalout) {
    const bool isf32 = detect_f32_block(hdet);
    const bool af32 = isf32 && (a_input != 0);
    const bool wf32 = isf32;
    const bool of32 = isf32 && (finalout != 0);

    const int wave = threadIdx.x >> 6;
    const int lane = threadIdx.x & 63;
    const int l16  = lane & 15;
    const int quad = lane >> 4;
    const int m0 = blockIdx.x * 64 + wave * 16;
    const int n0 = blockIdx.y * 64;

    f32x4 acc[4];
#pragma unroll
    for (int i = 0; i < 4; ++i) acc[i] = (f32x4){0.f, 0.f, 0.f, 0.f};

    const size_t aoff = (size_t)(m0 + l16) * D_MODEL + quad * 8;
    size_t woff[4];
#pragma unroll
    for (int nt = 0; nt < 4; ++nt)
        woff[nt] = (size_t)(n0 + nt * 16 + l16) * D_MODEL + quad * 8;

    for (int k0 = 0; k0 < D_MODEL; k0 += 32) {
        bf16x8 a = load_frag(af32, Ap, aoff + k0);
#pragma unroll
        for (int nt = 0; nt < 4; ++nt) {
            bf16x8 b = load_frag(wf32, Wp, woff[nt] + k0);
            acc[nt] = MFMA16(a, b, acc[nt]);
        }
    }

#pragma unroll
    for (int r = 0; r < 4; ++r) {
        const int m = m0 + quad * 4 + r;
        float vals[4];
#pragma unroll
        for (int nt = 0; nt < 4; ++nt) vals[nt] = acc[nt][r];
        float outv[4];
        if (rope) {
            rope4(vals, outv, m, l16);
        } else {
#pragma unroll
            for (int nt = 0; nt < 4; ++nt) outv[nt] = vals[nt];
        }
        const size_t crow = (size_t)m * N + n0;
        if (of32) {
            float* cp = (float*)Cp + crow;
#pragma unroll
            for (int nt = 0; nt < 4; ++nt) cp[nt * 16 + l16] = outv[nt];
        } else {
            unsigned short* cp = (unsigned short*)Cp + crow;
#pragma unroll
            for (int nt = 0; nt < 4; ++nt) cp[nt * 16 + l16] = f2bf(outv[nt]);
        }
    }
}

__global__ __launch_bounds__(256) void attn_kernel(const unsigned short* __restrict__ Q,
                                                   const unsigned short* __restrict__ Kb,
                                                   const unsigned short* __restrict__ Vb,
                                                   unsigned short* __restrict__ O, int kvs) {
    __shared__ unsigned short lp[4][16][32];

    const int wave = threadIdx.x >> 6;
    const int lane = threadIdx.x & 63;
    const int l16  = lane & 15;
    const int quad = lane >> 4;

    const int bid = blockIdx.x;
    const int qb  = bid & 31;
    const int h   = (bid >> 5) & 31;
    const int b   = bid >> 10;
    const int kvh = h >> 2;
    const int q0  = qb * 64 + wave * 16;

    const unsigned short* qbase = Q + (size_t)b * S_LEN * D_MODEL + h * HEAD_DIM;
    const unsigned short* kbase = Kb + (size_t)b * S_LEN * kvs + kvh * HEAD_DIM;
    const unsigned short* vbase = Vb + (size_t)b * S_LEN * kvs + kvh * HEAD_DIM;

    bf16x8 aq0 = *reinterpret_cast<const bf16x8*>(qbase + (size_t)(q0 + l16) * D_MODEL + quad * 8);
    bf16x8 aq1 = *reinterpret_cast<const bf16x8*>(qbase + (size_t)(q0 + l16) * D_MODEL + 32 + quad * 8);

    f32x4 o[4];
#pragma unroll
    for (int i = 0; i < 4; ++i) o[i] = (f32x4){0.f, 0.f, 0.f, 0.f};
    float mrow[4], lrow[4];
#pragma unroll
    for (int r = 0; r < 4; ++r) { mrow[r] = -3.0e38f; lrow[r] = 0.f; }

    const int kv_hi = qb * 64 + 64;
    for (int k0 = 0; k0 < kv_hi; k0 += 32) {
        f32x4 sc[2];
#pragma unroll
        for (int t = 0; t < 2; ++t) {
            const unsigned short* krow = kbase + (size_t)(k0 + t * 16 + l16) * kvs;
            bf16x8 b0 = *reinterpret_cast<const bf16x8*>(krow + quad * 8);
            bf16x8 b1 = *reinterpret_cast<const bf16x8*>(krow + 32 + quad * 8);
            f32x4 c = (f32x4){0.f, 0.f, 0.f, 0.f};
            c = MFMA16(aq0, b0, c);
            c = MFMA16(aq1, b1, c);
            sc[t] = c;
        }

        float alpha[4], p0v[4], p1v[4];
#pragma unroll
        for (int r = 0; r < 4; ++r) {
            const int qi = q0 + quad * 4 + r;
            float s0 = sc[0][r] * 0.125f;
            float s1 = sc[1][r] * 0.125f;
            if (k0 + l16 > qi)       s0 = -1.0e30f;
            if (k0 + 16 + l16 > qi)  s1 = -1.0e30f;
            float mt = fmaxf(s0, s1);
#pragma unroll
            for (int off = 1; off < 16; off <<= 1) mt = fmaxf(mt, __shfl_xor(mt, off, 64));
            const float mn = fmaxf(mrow[r], mt);
            const float al = __expf(mrow[r] - mn);
            const float p0 = __expf(s0 - mn);
            const float p1 = __expf(s1 - mn);
            float rs = p0 + p1;
#pragma unroll
            for (int off = 1; off < 16; off <<= 1) rs += __shfl_xor(rs, off, 64);
            lrow[r] = lrow[r] * al + rs;
            mrow[r] = mn;
            alpha[r] = al;
            p0v[r] = p0; p1v[r] = p1;
        }
#pragma unroll
        for (int nt = 0; nt < 4; ++nt)
#pragma unroll
            for (int r = 0; r < 4; ++r) o[nt][r] *= alpha[r];

        __syncthreads();
#pragma unroll
        for (int r = 0; r < 4; ++r) {
            lp[wave][quad * 4 + r][l16]      = f2bf(p0v[r]);
            lp[wave][quad * 4 + r][16 + l16] = f2bf(p1v[r]);
        }
        __syncthreads();
        bf16x8 ap = *reinterpret_cast<const bf16x8*>(&lp[wave][l16][quad * 8]);

#pragma unroll
        for (int nt = 0; nt < 4; ++nt) {
            const unsigned short* vcol = vbase + nt * 16 + l16 + (size_t)(k0 + quad * 8) * kvs;
            bf16x8 bv;
#pragma unroll
            for (int j = 0; j < 8; ++j) bv[j] = (short)vcol[(size_t)j * kvs];
            o[nt] = MFMA16(ap, bv, o[nt]);
        }
    }

    unsigned short* obase = O + (size_t)b * S_LEN * D_MODEL + h * HEAD_DIM;
#pragma unroll
    for (int r = 0; r < 4; ++r) {
        const float inv_l = 1.0f / lrow[r];
        unsigned short* orow = obase + (size_t)(q0 + quad * 4 + r) * D_MODEL;
#pragma unroll
        for (int nt = 0; nt < 4; ++nt)
            orow[nt * 16 + l16] = f2bf(o[nt][r] * inv_l);
    }
}

extern "C" void kernel_launch(void* const* d_in, const int* in_sizes, int n_in,
                              void* d_out, int out_size, void* d_ws, size_t ws_size,
                              hipStream_t stream) {
    const void* hidden = d_in[0];
    const void* Wq = d_in[1];
    const void* Wk = d_in[2];
    const void* Wv = d_in[3];
    const void* Wo = d_in[4];
    // d_in[5] = attention_mask: pure causal -1e9 -> implemented directly.

    char* ws = (char*)d_ws;
    dim3 blk(256);

    // kv 8MB + abuf 16MB + hbuf 16MB + wq 8MB + wkv 4MB + wo 8MB + vt 4MB + tab 512KB
    const size_t NEED = 1024 + ((size_t)64 << 20) + (512u << 10);
    if (ws_size >= NEED) {
        unsigned short* kvbuf = (unsigned short*)(ws + 1024);      // [4096,1024]: K cols 0-511, V cols 512-1023
        unsigned short* abuf  = kvbuf + (size_t)4096 * 1024;       // [4096,2048]
        unsigned short* hbuf  = abuf + (size_t)4096 * 2048;        // hidden bf16
        unsigned short* wqb   = hbuf + (size_t)4096 * 2048;        // [2048,2048]  } contiguous =
        unsigned short* wkvb  = wqb + (size_t)2048 * 2048;         // [1024,2048]  } Wqkv [3072,2048]
        unsigned short* wob   = wkvb + (size_t)1024 * 2048;        // [2048,2048]
        unsigned short* vtbuf = wob + (size_t)2048 * 2048;         // [2,512,2048] V^T
        float2* ropetab       = (float2*)(vtbuf + (size_t)2 * 512 * 2048);  // [2048][32]
        unsigned short* qbuf  = (unsigned short*)d_out;            // Q bf16 lives in d_out

        cvt_all<<<dim3(2048), blk, 0, stream>>>(hidden, Wq, Wk, Wv, Wo,
                                                hbuf, wqb, wkvb, wob, ropetab);

        gemm_qkv_lds<<<dim3(32, 24), blk, 0, stream>>>(hbuf, wqb, qbuf, kvbuf, ropetab);
        transpose_v<<<dim3(512), blk, 0, stream>>>(kvbuf + 512, vtbuf);
        attn_kernel7<<<dim3(2 * NHEAD * (S_LEN / 128)), blk, 0, stream>>>(qbuf, kvbuf, vtbuf, abuf, 1024);
        gemm_bt_lds<<<dim3(32, 16), blk, 0, stream>>>(abuf, wob, d_out, 2048,
                                                      (const unsigned short*)hidden, 0, 1);
    } else {
        // legacy 24MB path
        unsigned short* kbuf = (unsigned short*)(ws + 1024);
        unsigned short* vbuf = (unsigned short*)(ws + 1024 + (4u << 20));
        unsigned short* abuf = (unsigned short*)(ws + 1024 + (8u << 20));
        unsigned short* qbuf = (unsigned short*)d_out;
        const unsigned short* hdet = (const unsigned short*)hidden;
        gemm_bt<<<dim3(M_ROWS / 64, D_MODEL / 64), blk, 0, stream>>>(hidden, Wq, qbuf, D_MODEL, hdet, 1, 1, 0);
        gemm_bt<<<dim3(M_ROWS / 64, (NKVH * HEAD_DIM) / 64), blk, 0, stream>>>(hidden, Wk, kbuf, NKVH * HEAD_DIM, hdet, 1, 1, 0);
        gemm_bt<<<dim3(M_ROWS / 64, (NKVH * HEAD_DIM) / 64), blk, 0, stream>>>(hidden, Wv, vbuf, NKVH * HEAD_DIM, hdet, 1, 0, 0);
        attn_kernel<<<dim3(2 * NHEAD * (S_LEN / 64)), blk, 0, stream>>>(qbuf, kbuf, vbuf, abuf, 512);
        gemm_bt<<<dim3(M_ROWS / 64, D_MODEL / 64), blk, 0, stream>>>(abuf, Wo, d_out, D_MODEL, hdet, 0, 0, 1);
    }
}

// Round 11
// 422.683 us; speedup vs baseline: 2.6463x; 1.0026x over previous
//
#include <hip/hip_runtime.h>

// FlashAttentionWrapper: B=2, S=2048, D=2048, NH=32, HD=64, NKV=8, NREP=4,
// causal, RoPE theta=1e4. Input dtype (bf16/f32) self-detected per block.
// New-path workspace (64MB+1KB+512KB):
//   [1KB pad][kvbuf 4096x1024 8MB][abuf 4096x2048 16MB]
//   [hbuf 16MB][wqb 8MB][wkvb 4MB][wob 8MB][vtbuf 2x512x2048 4MB]
//   [ropetab 2048x32 float2 512KB]
// wqb+wkvb are CONTIGUOUS => one [3072,2048] QKV weight matrix (fused GEMM).
// Q-projection result lives in d_out (dead before O-proj overwrites it).
// Fallback path (ws too small): original direct-load kernels, 24MB+1KB.
//
// Round-5 lesson: hand-written v_cvt_pk_bf16_f32 asm mis-packed (absmax 3.6).
// Round-8 lesson: forced launch_bounds occupancy => scratch spill (32x traffic).
// Round-10 lesson: 2-phase GEMM dbuf null — m97 structure is at its shape
// ceiling (m102: ~320-450 TF at K=2048); GEMM parked.
// Round-11: attention exp path. Counter math: VALUBusy 37% => ~900 VALU
// inst/tile, 3x the hand count; prime suspect is fexp2 silently compiling to
// the PRECISE exp2f libcall (__builtin_amdgcn_exp2f may not exist =>
// __has_builtin=0). Switch softmax to natural-log domain with __expf (HIP
// native intrinsic, v_mul+v_exp_f32 guaranteed). THR = 8*ln2 (same 2^8 bound).

#define S_LEN 2048
#define D_MODEL 2048
#define NHEAD 32
#define HEAD_DIM 64
#define NKVH 8
#define M_ROWS 4096   // B*S
#define KVW (NKVH * HEAD_DIM)   // 512

typedef __attribute__((ext_vector_type(4))) float f32x4;
typedef __attribute__((ext_vector_type(8))) short bf16x8;

#define MFMA16(a, b, c) __builtin_amdgcn_mfma_f32_16x16x32_bf16((a), (b), (c), 0, 0, 0)

// async global->LDS, 16B per lane; LDS dest is wave-uniform base + lane*16
#define GLOAD_LDS16(g, l)                                                     \
    __builtin_amdgcn_global_load_lds(                                         \
        (const __attribute__((address_space(1))) void*)(g),                   \
        (__attribute__((address_space(3))) void*)(l), 16, 0, 0)

// f32 -> bf16 RNE via native cast (compiler emits the HW convert).
static __device__ __forceinline__ unsigned short f2bf(float f) {
    union { __bf16 b; unsigned short u; } v;
    v.b = (__bf16)f;
    return v.u;
}

// XCD-chunked swizzle of a 2D grid (requires gridDim.x*gridDim.y % 8 == 0).
static __device__ __forceinline__ void xcd_swz(int& bx, int& by) {
    const int gx = gridDim.x;
    const int nwg = gx * gridDim.y;
    int lin = blockIdx.y * gx + blockIdx.x;
    lin = (lin & 7) * (nwg >> 3) + (lin >> 3);
    bx = lin % gx;
    by = lin / gx;
}

// ---------------------------------------------------------------------------
// Per-block dtype self-detection: f32 data read as uint16 shows impossible
// bf16 exponents at even indices. Called uniformly by all 256 threads.
// ---------------------------------------------------------------------------
static __device__ bool detect_f32_block(const unsigned short* __restrict__ h) {
    __shared__ int dcnt;
    if (threadIdx.x == 0) dcnt = 0;
    __syncthreads();
    const unsigned short v = h[2 * (threadIdx.x & 255)];
    const int e = (v >> 7) & 0xFF;
    if (threadIdx.x < 256 && e >= 0x8D) atomicAdd(&dcnt, 1);
    __syncthreads();
    return dcnt >= 8;
}

static __device__ __forceinline__ bf16x8 load_frag(bool f32p, const void* p, size_t off) {
    if (f32p) {
        const float* fp = (const float*)p + off;
        f32x4 x = *reinterpret_cast<const f32x4*>(fp);
        f32x4 y = *reinterpret_cast<const f32x4*>(fp + 4);
        bf16x8 r;
        r[0] = (short)f2bf(x[0]); r[1] = (short)f2bf(x[1]);
        r[2] = (short)f2bf(x[2]); r[3] = (short)f2bf(x[3]);
        r[4] = (short)f2bf(y[0]); r[5] = (short)f2bf(y[1]);
        r[6] = (short)f2bf(y[2]); r[7] = (short)f2bf(y[3]);
        return r;
    }
    return *reinterpret_cast<const bf16x8*>((const unsigned short*)p + off);
}

// ---------------------------------------------------------------------------
// Fused one-time f32->bf16 conversion (or bf16 copy) of all 5 operands,
// plus the RoPE cos/sin table (tab[s*32+dd] = cos/sin of s*10000^(-dd/32)).
// ---------------------------------------------------------------------------
__global__ __launch_bounds__(256) void cvt_all(const void* __restrict__ h,
                                               const void* __restrict__ wq,
                                               const void* __restrict__ wk,
                                               const void* __restrict__ wv,
                                               const void* __restrict__ wo,
                                               unsigned short* __restrict__ hbuf,
                                               unsigned short* __restrict__ wqb,
                                               unsigned short* __restrict__ wkvb,
                                               unsigned short* __restrict__ wob,
                                               float2* __restrict__ ropetab) {
    const bool f32p = detect_f32_block((const unsigned short*)h);
    const int e0 = 1048576;            // hidden 4096x2048
    const int e1 = e0 + 524288;        // Wq 2048x2048
    const int e2 = e1 + 131072;        // Wk 512x2048
    const int e3 = e2 + 131072;        // Wv 512x2048
    const int e4 = e3 + 524288;        // Wo 2048x2048
    const int e5 = e4 + 8192;          // rope table 2048x32 (8 entries/unit)
    int i = blockIdx.x * 256 + threadIdx.x;
    const int stride = gridDim.x * 256;
    for (; i < e5; i += stride) {
        if (i >= e4) {
            const int base = (i - e4) * 8;
#pragma unroll
            for (int j = 0; j < 8; ++j) {
                const int idx = base + j;
                const int s = idx >> 5, dd = idx & 31;
                const float inv = exp2f(-(float)dd * 0.4152410118609203f);
                const float th = (float)s * inv;
                float sn, cs;
                sincosf(th, &sn, &cs);
                ropetab[idx] = make_float2(cs, sn);
            }
            continue;
        }
        const void* s;
        unsigned short* d;
        size_t off;
        if (i < e0)      { s = h;  d = hbuf; off = (size_t)i; }
        else if (i < e1) { s = wq; d = wqb;  off = (size_t)(i - e0); }
        else if (i < e2) { s = wk; d = wkvb; off = (size_t)(i - e1); }
        else if (i < e3) { s = wv; d = wkvb + (size_t)512 * 2048; off = (size_t)(i - e2); }
        else             { s = wo; d = wob;  off = (size_t)(i - e3); }
        bf16x8 v = load_frag(f32p, s, off * 8);
        *reinterpret_cast<bf16x8*>(d + off * 8) = v;
    }
}

// ---------------------------------------------------------------------------
// RoPE epilogue helpers.
// ---------------------------------------------------------------------------
static __device__ __forceinline__ void rope4_tab(const float2* __restrict__ tab,
                                                 const float (&vals)[4], float (&outv)[4],
                                                 int m, int l16) {
    const int s = m & (S_LEN - 1);
#pragma unroll
    for (int nt = 0; nt < 4; ++nt) {
        const int d = nt * 16 + l16;
        const float2 cs = tab[s * 32 + (d & 31)];
        const float part = vals[nt ^ 2];
        const float rot = (nt < 2) ? -part : part;  // d<32: -x2 ; d>=32: +x1
        outv[nt] = vals[nt] * cs.x + rot * cs.y;
    }
}

static __device__ __forceinline__ void rope4(const float (&vals)[4], float (&outv)[4],
                                             int m, int l16) {
    const float sf = (float)(m & (S_LEN - 1));
#pragma unroll
    for (int nt = 0; nt < 4; ++nt) {
        const int d = nt * 16 + l16;
        const float inv = exp2f(-(float)(d & 31) * 0.4152410118609203f);
        const float th = sf * inv;
        float sn, cs;
        sincosf(th, &sn, &cs);
        const float part = vals[nt ^ 2];
        const float rot = (nt < 2) ? -part : part;
        outv[nt] = vals[nt] * cs + rot * sn;
    }
}

// ---------------------------------------------------------------------------
// 2-phase double-buffered GEMM core (kept from round 10; null but harmless).
// ---------------------------------------------------------------------------
#define GEMM_STAGE(BB, KK)                                                    \
    {                                                                         \
        _Pragma("unroll")                                                     \
        for (int i_ = 0; i_ < 2; ++i_) {                                      \
            const int c_ = wave * 2 + i_;                                     \
            GLOAD_LDS16(ag[i_] + (KK), &lds_a[BB][c_ * 512]);                 \
            GLOAD_LDS16(wg[i_] + (KK), &lds_b[BB][c_ * 512]);                 \
        }                                                                     \
    }

#define GEMM_MAINLOOP()                                                       \
    GEMM_STAGE(0, 0);                                                         \
    __syncthreads();                                                          \
    {                                                                         \
        int cur = 0;                                                          \
        for (int k0 = 0; k0 < D_MODEL; k0 += 32) {                            \
            if (k0 + 32 < D_MODEL) GEMM_STAGE(cur ^ 1, k0 + 32);              \
            bf16x8 af[4], bfm[4];                                             \
            _Pragma("unroll")                                                 \
            for (int t = 0; t < 4; ++t) {                                     \
                af[t]  = *reinterpret_cast<const bf16x8*>(                    \
                    &lds_a[cur][(wm * 64 + t * 16 + l16) * 32 + quad * 8]);   \
                bfm[t] = *reinterpret_cast<const bf16x8*>(                    \
                    &lds_b[cur][(wn * 64 + t * 16 + l16) * 32 + quad * 8]);   \
            }                                                                 \
            _Pragma("unroll")                                                 \
            for (int mt = 0; mt < 4; ++mt)                                    \
                _Pragma("unroll")                                             \
                for (int nt = 0; nt < 4; ++nt)                                \
                    acc[mt][nt] = MFMA16(af[mt], bfm[nt], acc[mt][nt]);       \
            __syncthreads();                                                  \
            cur ^= 1;                                                         \
        }                                                                     \
    }

// ---------------------------------------------------------------------------
// Fused QKV GEMM: A[4096,2048] @ Wqkv[3072,2048]^T, all bf16. 128x128 tile,
// BK=32, 4 waves 2x2, 2-phase dbuf staging, XCD swizzle.
// ---------------------------------------------------------------------------
__global__ __launch_bounds__(256) void gemm_qkv_lds(const unsigned short* __restrict__ A,
                                                    const unsigned short* __restrict__ W,
                                                    unsigned short* __restrict__ Qo,
                                                    unsigned short* __restrict__ KVo,
                                                    const float2* __restrict__ ropetab) {
    __shared__ unsigned short lds_a[2][128 * 32];   // 2 x 8KB
    __shared__ unsigned short lds_b[2][128 * 32];   // 2 x 8KB

    const int wave = threadIdx.x >> 6;
    const int lane = threadIdx.x & 63;
    const int l16  = lane & 15;
    const int quad = lane >> 4;
    const int wm   = wave >> 1;
    const int wn   = wave & 1;

    int bx, by;
    xcd_swz(bx, by);
    const int m0 = bx * 128;
    const int n0 = by * 128;

    const int srow = lane >> 2;
    const int scol = (lane & 3) * 8;
    const unsigned short* ag[2];
    const unsigned short* wg[2];
#pragma unroll
    for (int i = 0; i < 2; ++i) {
        const int c = wave * 2 + i;
        ag[i] = A + (size_t)(m0 + c * 16 + srow) * D_MODEL + scol;
        wg[i] = W + (size_t)(n0 + c * 16 + srow) * D_MODEL + scol;
    }

    f32x4 acc[4][4];
#pragma unroll
    for (int i = 0; i < 4; ++i)
#pragma unroll
        for (int j = 0; j < 4; ++j) acc[i][j] = (f32x4){0.f, 0.f, 0.f, 0.f};

    GEMM_MAINLOOP();

    const int ncol0 = n0 + wn * 64;                 // wave-uniform, head-aligned
    const bool do_rope = (ncol0 < 2048 + KVW);      // Q and K regions
    unsigned short* dst;
    int cstride, c0;
    if (ncol0 < 2048) { dst = Qo;  cstride = 2048; c0 = ncol0; }
    else              { dst = KVo; cstride = 1024; c0 = ncol0 - 2048; }

#pragma unroll
    for (int mt = 0; mt < 4; ++mt) {
#pragma unroll
        for (int r = 0; r < 4; ++r) {
            const int m = m0 + wm * 64 + mt * 16 + quad * 4 + r;
            float vals[4];
#pragma unroll
            for (int nt = 0; nt < 4; ++nt) vals[nt] = acc[mt][nt][r];
            float outv[4];
            if (do_rope) {
                rope4_tab(ropetab, vals, outv, m, l16);
            } else {
#pragma unroll
                for (int nt = 0; nt < 4; ++nt) outv[nt] = vals[nt];
            }
            unsigned short* cp = dst + (size_t)m * cstride + c0;
#pragma unroll
            for (int nt = 0; nt < 4; ++nt) cp[nt * 16 + l16] = f2bf(outv[nt]);
        }
    }
}

// ---------------------------------------------------------------------------
// O-projection GEMM: C[M,N] = A[M,2048] @ W[N,2048]^T, bf16, 2-phase dbuf,
// XCD swizzle. finalout + f32 input -> f32 output (dtype via self-detect).
// ---------------------------------------------------------------------------
__global__ __launch_bounds__(256) void gemm_bt_lds(const unsigned short* __restrict__ A,
                                                   const unsigned short* __restrict__ W,
                                                   void* __restrict__ Cp, int N,
                                                   const unsigned short* __restrict__ hdet,
                                                   int rope, int finalout) {
    __shared__ unsigned short lds_a[2][128 * 32];
    __shared__ unsigned short lds_b[2][128 * 32];

    bool of32 = false;
    if (finalout) of32 = detect_f32_block(hdet);

    const int wave = threadIdx.x >> 6;
    const int lane = threadIdx.x & 63;
    const int l16  = lane & 15;
    const int quad = lane >> 4;
    const int wm   = wave >> 1;
    const int wn   = wave & 1;

    int bx, by;
    xcd_swz(bx, by);
    const int m0 = bx * 128;
    const int n0 = by * 128;

    const int srow = lane >> 2;
    const int scol = (lane & 3) * 8;
    const unsigned short* ag[2];
    const unsigned short* wg[2];
#pragma unroll
    for (int i = 0; i < 2; ++i) {
        const int c = wave * 2 + i;
        ag[i] = A + (size_t)(m0 + c * 16 + srow) * D_MODEL + scol;
        wg[i] = W + (size_t)(n0 + c * 16 + srow) * D_MODEL + scol;
    }

    f32x4 acc[4][4];
#pragma unroll
    for (int i = 0; i < 4; ++i)
#pragma unroll
        for (int j = 0; j < 4; ++j) acc[i][j] = (f32x4){0.f, 0.f, 0.f, 0.f};

    GEMM_MAINLOOP();

    const bool do_rope = (rope != 0);
    const int ncol0 = n0 + wn * 64;

#pragma unroll
    for (int mt = 0; mt < 4; ++mt) {
#pragma unroll
        for (int r = 0; r < 4; ++r) {
            const int m = m0 + wm * 64 + mt * 16 + quad * 4 + r;
            float vals[4];
#pragma unroll
            for (int nt = 0; nt < 4; ++nt) vals[nt] = acc[mt][nt][r];
            float outv[4];
            if (do_rope) {
                rope4(vals, outv, m, l16);
            } else {
#pragma unroll
                for (int nt = 0; nt < 4; ++nt) outv[nt] = vals[nt];
            }
            const size_t crow = (size_t)m * N + ncol0;
            if (of32) {
                float* cp = (float*)Cp + crow;
#pragma unroll
                for (int nt = 0; nt < 4; ++nt) cp[nt * 16 + l16] = outv[nt];
            } else {
                unsigned short* cp = (unsigned short*)Cp + crow;
#pragma unroll
                for (int nt = 0; nt < 4; ++nt) cp[nt * 16 + l16] = f2bf(outv[nt]);
            }
        }
    }
}

// ---------------------------------------------------------------------------
// V transpose: Vsrc = kvbuf V-half [B*S rows, stride 1024] cols 0..511
//   -> Vt[b][c][s] ([B][512][S]).  64x64 LDS tiles, fully coalesced.
// ---------------------------------------------------------------------------
__global__ __launch_bounds__(256) void transpose_v(const unsigned short* __restrict__ Vsrc,
                                                   unsigned short* __restrict__ Vt) {
    __shared__ unsigned short t[64][72];
    const int bid = blockIdx.x;
    const int ct = bid & 7;
    const int st = (bid >> 3) & 31;
    const int b  = bid >> 8;
    const unsigned short* src = Vsrc + ((size_t)b * S_LEN + st * 64) * 1024 + ct * 64;
    unsigned short* dst = Vt + ((size_t)b * KVW + ct * 64) * S_LEN + st * 64;
    const int r0 = threadIdx.x >> 3;
    const int c0 = (threadIdx.x & 7) * 8;
#pragma unroll
    for (int h = 0; h < 2; ++h) {
        bf16x8 v = *reinterpret_cast<const bf16x8*>(src + (size_t)(r0 + h * 32) * 1024 + c0);
        *reinterpret_cast<bf16x8*>(&t[r0 + h * 32][c0]) = v;
    }
    __syncthreads();
#pragma unroll
    for (int h = 0; h < 2; ++h) {
        const int cr = r0 + h * 32;
        bf16x8 v;
#pragma unroll
        for (int j = 0; j < 8; ++j) v[j] = (short)t[c0 + j][cr];
        *reinterpret_cast<bf16x8*>(dst + (size_t)cr * S_LEN + c0) = v;
    }
}

// ---------------------------------------------------------------------------
// Flash attention v8: round-9 verified structure (single-buffered K, vf-early,
// row-sum via MFMA, deferred max), softmax in NATURAL-log domain with __expf
// (native v_mul+v_exp_f32) instead of exp2f (possible precise-libcall per the
// round-11 counter math). THR = 8*ln2 keeps the identical 2^8 P-bound.
// ---------------------------------------------------------------------------
struct AttnCtx {
    const unsigned short* qbase;
    const unsigned short* kbase;
    const unsigned short* vtbase;
    unsigned short* obase;
    int kvs;
    int l16, quad;
    unsigned short (*lpw)[72];   // [32][72] per-wave slice
};

#define SM_SCALE 0.125f               // 1/sqrt(HD)
#define SM_THR_E 5.545177444479562f   // 8 * ln2

static __device__ __forceinline__ void attn_qtile(const AttnCtx& cx, int q0w) {
    const int l16 = cx.l16, quad = cx.quad;
    const int kvs = cx.kvs;

    bf16x8 ones;
#pragma unroll
    for (int j = 0; j < 8; ++j) ones[j] = (short)0x3F80;   // bf16 1.0

    bf16x8 aq[2][2];
#pragma unroll
    for (int m = 0; m < 2; ++m)
#pragma unroll
        for (int kh = 0; kh < 2; ++kh)
            aq[m][kh] = *reinterpret_cast<const bf16x8*>(
                cx.qbase + (size_t)(q0w + m * 16 + l16) * D_MODEL + kh * 32 + quad * 8);

    f32x4 o[2][4];
    f32x4 c_l[2];     // row-sum accumulator (l = P @ ones)
#pragma unroll
    for (int m = 0; m < 2; ++m) {
#pragma unroll
        for (int i = 0; i < 4; ++i) o[m][i] = (f32x4){0.f, 0.f, 0.f, 0.f};
        c_l[m] = (f32x4){0.f, 0.f, 0.f, 0.f};
    }
    float m2[2][4];   // running max, natural-log domain
#pragma unroll
    for (int m = 0; m < 2; ++m)
#pragma unroll
        for (int r = 0; r < 4; ++r) m2[m][r] = 0.f;

    const int kv_hi = q0w + 32;   // per-wave causal bound

    for (int k0 = 0; k0 < kv_hi; k0 += 64) {
        // ---- K fragments (single buffer; regs freed after QK^T) ----
        bf16x8 kf[8];
#pragma unroll
        for (int t = 0; t < 4; ++t) {
            const unsigned short* krow = cx.kbase + (size_t)(k0 + t * 16 + l16) * kvs;
            kf[2 * t]     = *reinterpret_cast<const bf16x8*>(krow + quad * 8);
            kf[2 * t + 1] = *reinterpret_cast<const bf16x8*>(krow + 32 + quad * 8);
        }

        f32x4 sc[2][4];
        __builtin_amdgcn_s_setprio(1);
#pragma unroll
        for (int t = 0; t < 4; ++t) {
#pragma unroll
            for (int m = 0; m < 2; ++m) {
                f32x4 c = (f32x4){0.f, 0.f, 0.f, 0.f};
                c = MFMA16(aq[m][0], kf[2 * t], c);
                c = MFMA16(aq[m][1], kf[2 * t + 1], c);
                sc[m][t] = c;
            }
        }
        __builtin_amdgcn_s_setprio(0);

        // ---- V fragments issued early (cover latency under softmax) ----
        bf16x8 vf[8];
#pragma unroll
        for (int nt = 0; nt < 4; ++nt) {
            const unsigned short* vrow =
                cx.vtbase + (size_t)(nt * 16 + l16) * S_LEN + k0 + quad * 8;
            vf[2 * nt]     = *reinterpret_cast<const bf16x8*>(vrow);
            vf[2 * nt + 1] = *reinterpret_cast<const bf16x8*>(vrow + 32);
        }

        const bool full = (k0 + 63 <= q0w);
        float pm[2][4];
        float dif = -3.0e38f;
#pragma unroll
        for (int m = 0; m < 2; ++m) {
#pragma unroll
            for (int r = 0; r < 4; ++r) {
                const int qi = q0w + m * 16 + quad * 4 + r;
                float s[4];
#pragma unroll
                for (int t = 0; t < 4; ++t) {
                    s[t] = sc[m][t][r] * SM_SCALE;
                    if (!full && (k0 + t * 16 + l16 > qi)) s[t] = -1.0e30f;
                    sc[m][t][r] = s[t];
                }
                const float p = fmaxf(fmaxf(s[0], s[1]), fmaxf(s[2], s[3]));
                pm[m][r] = p;
                dif = fmaxf(dif, p - m2[m][r]);
            }
        }
        if (__any(dif > SM_THR_E)) {
#pragma unroll
            for (int m = 0; m < 2; ++m) {
#pragma unroll
                for (int r = 0; r < 4; ++r) {
                    float mt = pm[m][r];
#pragma unroll
                    for (int off = 1; off < 16; off <<= 1)
                        mt = fmaxf(mt, __shfl_xor(mt, off, 64));
                    const float mn = fmaxf(m2[m][r], mt);
                    const float al = __expf(m2[m][r] - mn);
                    m2[m][r] = mn;
#pragma unroll
                    for (int nt = 0; nt < 4; ++nt) o[m][nt][r] *= al;
                    c_l[m][r] *= al;
                }
            }
        }
        // pass 2: p = exp(s - m2), write P tile
#pragma unroll
        for (int m = 0; m < 2; ++m) {
#pragma unroll
            for (int r = 0; r < 4; ++r) {
                const float mb = m2[m][r];
#pragma unroll
                for (int t = 0; t < 4; ++t) {
                    const float pv = __expf(sc[m][t][r] - mb);
                    cx.lpw[m * 16 + quad * 4 + r][t * 16 + l16] = f2bf(pv);
                }
            }
        }
        asm volatile("" ::: "memory");
        bf16x8 ap[2][2];
#pragma unroll
        for (int m = 0; m < 2; ++m)
#pragma unroll
            for (int kh = 0; kh < 2; ++kh)
                ap[m][kh] = *reinterpret_cast<const bf16x8*>(
                    &cx.lpw[m * 16 + l16][kh * 32 + quad * 8]);
        __builtin_amdgcn_s_setprio(1);
#pragma unroll
        for (int nt = 0; nt < 4; ++nt)
#pragma unroll
            for (int m = 0; m < 2; ++m) {
                o[m][nt] = MFMA16(ap[m][0], vf[2 * nt], o[m][nt]);
                o[m][nt] = MFMA16(ap[m][1], vf[2 * nt + 1], o[m][nt]);
            }
#pragma unroll
        for (int m = 0; m < 2; ++m) {
            c_l[m] = MFMA16(ap[m][0], ones, c_l[m]);
            c_l[m] = MFMA16(ap[m][1], ones, c_l[m]);
        }
        __builtin_amdgcn_s_setprio(0);
    }

#pragma unroll
    for (int m = 0; m < 2; ++m)
#pragma unroll
        for (int r = 0; r < 4; ++r) {
            const float inv_l = 1.0f / c_l[m][r];
            unsigned short* orow = cx.obase + (size_t)(q0w + m * 16 + quad * 4 + r) * D_MODEL;
#pragma unroll
            for (int nt = 0; nt < 4; ++nt)
                orow[nt * 16 + l16] = f2bf(o[m][nt][r] * inv_l);
        }
}

__global__ __launch_bounds__(256) void attn_kernel8(const unsigned short* __restrict__ Q,
                                                    const unsigned short* __restrict__ Kb,
                                                    const unsigned short* __restrict__ Vt,
                                                    unsigned short* __restrict__ O, int kvs) {
    __shared__ unsigned short lp[4][32][72];   // per-wave P (32 q x 64 k), padded

    const int wave = threadIdx.x >> 6;
    const int lane = threadIdx.x & 63;

    const int bid  = blockIdx.x;
    const int qt   = 15 - (bid >> 6);
    const int bh   = bid & 63;
    const int h    = bh & (NHEAD - 1);
    const int b    = bh >> 5;
    const int kvh  = h >> 2;

    AttnCtx cx;
    cx.qbase  = Q + (size_t)b * S_LEN * D_MODEL + h * HEAD_DIM;
    cx.kbase  = Kb + (size_t)b * S_LEN * kvs + kvh * HEAD_DIM;
    cx.vtbase = Vt + ((size_t)b * KVW + kvh * HEAD_DIM) * S_LEN;
    cx.obase  = O + (size_t)b * S_LEN * D_MODEL + h * HEAD_DIM;
    cx.kvs    = kvs;
    cx.l16    = lane & 15;
    cx.quad   = lane >> 4;
    cx.lpw    = lp[wave];

    attn_qtile(cx, qt * 128 + wave * 32);
}

// ---------------------------------------------------------------------------
// Legacy direct-load GEMM + attention (fallback path only).
// ---------------------------------------------------------------------------
__global__ __launch_bounds__(256) void gemm_bt(const void* __restrict__ Ap,
                                               const void* __restrict__ Wp,
                                               void* __restrict__ Cp, int N,
                                               const unsigned short* __restrict__ hdet,
                                               int a_input, int rope, int finalout) {
    const bool isf32 = detect_f32_block(hdet);
    const bool af32 = isf32 && (a_input != 0);
    const bool wf32 = isf32;
    const bool of32 = isf32 && (finalout != 0);

    const int wave = threadIdx.x >> 6;
    const int lane = threadIdx.x & 63;
    const int l16  = lane & 15;
    const int quad = lane >> 4;
    const int m0 = blockIdx.x * 64 + wave * 16;
    const int n0 = blockIdx.y * 64;

    f32x4 acc[4];
#pragma unroll
    for (int i = 0; i < 4; ++i) acc[i] = (f32x4){0.f, 0.f, 0.f, 0.f};

    const size_t aoff = (size_t)(m0 + l16) * D_MODEL + quad * 8;
    size_t woff[4];
#pragma unroll
    for (int nt = 0; nt < 4; ++nt)
        woff[nt] = (size_t)(n0 + nt * 16 + l16) * D_MODEL + quad * 8;

    for (int k0 = 0; k0 < D_MODEL; k0 += 32) {
        bf16x8 a = load_frag(af32, Ap, aoff + k0);
#pragma unroll
        for (int nt = 0; nt < 4; ++nt) {
            bf16x8 b = load_frag(wf32, Wp, woff[nt] + k0);
            acc[nt] = MFMA16(a, b, acc[nt]);
        }
    }

#pragma unroll
    for (int r = 0; r < 4; ++r) {
        const int m = m0 + quad * 4 + r;
        float vals[4];
#pragma unroll
        for (int nt = 0; nt < 4; ++nt) vals[nt] = acc[nt][r];
        float outv[4];
        if (rope) {
            rope4(vals, outv, m, l16);
        } else {
#pragma unroll
            for (int nt = 0; nt < 4; ++nt) outv[nt] = vals[nt];
        }
        const size_t crow = (size_t)m * N + n0;
        if (of32) {
            float* cp = (float*)Cp + crow;
#pragma unroll
            for (int nt = 0; nt < 4; ++nt) cp[nt * 16 + l16] = outv[nt];
        } else {
            unsigned short* cp = (unsigned short*)Cp + crow;
#pragma unroll
            for (int nt = 0; nt < 4; ++nt) cp[nt * 16 + l16] = f2bf(outv[nt]);
        }
    }
}

__global__ __launch_bounds__(256) void attn_kernel(const unsigned short* __restrict__ Q,
                                                   const unsigned short* __restrict__ Kb,
                                                   const unsigned short* __restrict__ Vb,
                                                   unsigned short* __restrict__ O, int kvs) {
    __shared__ unsigned short lp[4][16][32];

    const int wave = threadIdx.x >> 6;
    const int lane = threadIdx.x & 63;
    const int l16  = lane & 15;
    const int quad = lane >> 4;

    const int bid = blockIdx.x;
    const int qb  = bid & 31;
    const int h   = (bid >> 5) & 31;
    const int b   = bid >> 10;
    const int kvh = h >> 2;
    const int q0  = qb * 64 + wave * 16;

    const unsigned short* qbase = Q + (size_t)b * S_LEN * D_MODEL + h * HEAD_DIM;
    const unsigned short* kbase = Kb + (size_t)b * S_LEN * kvs + kvh * HEAD_DIM;
    const unsigned short* vbase = Vb + (size_t)b * S_LEN * kvs + kvh * HEAD_DIM;

    bf16x8 aq0 = *reinterpret_cast<const bf16x8*>(qbase + (size_t)(q0 + l16) * D_MODEL + quad * 8);
    bf16x8 aq1 = *reinterpret_cast<const bf16x8*>(qbase + (size_t)(q0 + l16) * D_MODEL + 32 + quad * 8);

    f32x4 o[4];
#pragma unroll
    for (int i = 0; i < 4; ++i) o[i] = (f32x4){0.f, 0.f, 0.f, 0.f};
    float mrow[4], lrow[4];
#pragma unroll
    for (int r = 0; r < 4; ++r) { mrow[r] = -3.0e38f; lrow[r] = 0.f; }

    const int kv_hi = qb * 64 + 64;
    for (int k0 = 0; k0 < kv_hi; k0 += 32) {
        f32x4 sc[2];
#pragma unroll
        for (int t = 0; t < 2; ++t) {
            const unsigned short* krow = kbase + (size_t)(k0 + t * 16 + l16) * kvs;
            bf16x8 b0 = *reinterpret_cast<const bf16x8*>(krow + quad * 8);
            bf16x8 b1 = *reinterpret_cast<const bf16x8*>(krow + 32 + quad * 8);
            f32x4 c = (f32x4){0.f, 0.f, 0.f, 0.f};
            c = MFMA16(aq0, b0, c);
            c = MFMA16(aq1, b1, c);
            sc[t] = c;
        }

        float alpha[4], p0v[4], p1v[4];
#pragma unroll
        for (int r = 0; r < 4; ++r) {
            const int qi = q0 + quad * 4 + r;
            float s0 = sc[0][r] * 0.125f;
            float s1 = sc[1][r] * 0.125f;
            if (k0 + l16 > qi)       s0 = -1.0e30f;
            if (k0 + 16 + l16 > qi)  s1 = -1.0e30f;
            float mt = fmaxf(s0, s1);
#pragma unroll
            for (int off = 1; off < 16; off <<= 1) mt = fmaxf(mt, __shfl_xor(mt, off, 64));
            const float mn = fmaxf(mrow[r], mt);
            const float al = __expf(mrow[r] - mn);
            const float p0 = __expf(s0 - mn);
            const float p1 = __expf(s1 - mn);
            float rs = p0 + p1;
#pragma unroll
            for (int off = 1; off < 16; off <<= 1) rs += __shfl_xor(rs, off, 64);
            lrow[r] = lrow[r] * al + rs;
            mrow[r] = mn;
            alpha[r] = al;
            p0v[r] = p0; p1v[r] = p1;
        }
#pragma unroll
        for (int nt = 0; nt < 4; ++nt)
#pragma unroll
            for (int r = 0; r < 4; ++r) o[nt][r] *= alpha[r];

        __syncthreads();
#pragma unroll
        for (int r = 0; r < 4; ++r) {
            lp[wave][quad * 4 + r][l16]      = f2bf(p0v[r]);
            lp[wave][quad * 4 + r][16 + l16] = f2bf(p1v[r]);
        }
        __syncthreads();
        bf16x8 ap = *reinterpret_cast<const bf16x8*>(&lp[wave][l16][quad * 8]);

#pragma unroll
        for (int nt = 0; nt < 4; ++nt) {
            const unsigned short* vcol = vbase + nt * 16 + l16 + (size_t)(k0 + quad * 8) * kvs;
            bf16x8 bv;
#pragma unroll
            for (int j = 0; j < 8; ++j) bv[j] = (short)vcol[(size_t)j * kvs];
            o[nt] = MFMA16(ap, bv, o[nt]);
        }
    }

    unsigned short* obase = O + (size_t)b * S_LEN * D_MODEL + h * HEAD_DIM;
#pragma unroll
    for (int r = 0; r < 4; ++r) {
        const float inv_l = 1.0f / lrow[r];
        unsigned short* orow = obase + (size_t)(q0 + quad * 4 + r) * D_MODEL;
#pragma unroll
        for (int nt = 0; nt < 4; ++nt)
            orow[nt * 16 + l16] = f2bf(o[nt][r] * inv_l);
    }
}

extern "C" void kernel_launch(void* const* d_in, const int* in_sizes, int n_in,
                              void* d_out, int out_size, void* d_ws, size_t ws_size,
                              hipStream_t stream) {
    const void* hidden = d_in[0];
    const void* Wq = d_in[1];
    const void* Wk = d_in[2];
    const void* Wv = d_in[3];
    const void* Wo = d_in[4];
    // d_in[5] = attention_mask: pure causal -1e9 -> implemented directly.

    char* ws = (char*)d_ws;
    dim3 blk(256);

    // kv 8MB + abuf 16MB + hbuf 16MB + wq 8MB + wkv 4MB + wo 8MB + vt 4MB + tab 512KB
    const size_t NEED = 1024 + ((size_t)64 << 20) + (512u << 10);
    if (ws_size >= NEED) {
        unsigned short* kvbuf = (unsigned short*)(ws + 1024);      // [4096,1024]: K cols 0-511, V cols 512-1023
        unsigned short* abuf  = kvbuf + (size_t)4096 * 1024;       // [4096,2048]
        unsigned short* hbuf  = abuf + (size_t)4096 * 2048;        // hidden bf16
        unsigned short* wqb   = hbuf + (size_t)4096 * 2048;        // [2048,2048]  } contiguous =
        unsigned short* wkvb  = wqb + (size_t)2048 * 2048;         // [1024,2048]  } Wqkv [3072,2048]
        unsigned short* wob   = wkvb + (size_t)1024 * 2048;        // [2048,2048]
        unsigned short* vtbuf = wob + (size_t)2048 * 2048;         // [2,512,2048] V^T
        float2* ropetab       = (float2*)(vtbuf + (size_t)2 * 512 * 2048);  // [2048][32]
        unsigned short* qbuf  = (unsigned short*)d_out;            // Q bf16 lives in d_out

        cvt_all<<<dim3(2048), blk, 0, stream>>>(hidden, Wq, Wk, Wv, Wo,
                                                hbuf, wqb, wkvb, wob, ropetab);

        gemm_qkv_lds<<<dim3(32, 24), blk, 0, stream>>>(hbuf, wqb, qbuf, kvbuf, ropetab);
        transpose_v<<<dim3(512), blk, 0, stream>>>(kvbuf + 512, vtbuf);
        attn_kernel8<<<dim3(2 * NHEAD * (S_LEN / 128)), blk, 0, stream>>>(qbuf, kvbuf, vtbuf, abuf, 1024);
        gemm_bt_lds<<<dim3(32, 16), blk, 0, stream>>>(abuf, wob, d_out, 2048,
                                                      (const unsigned short*)hidden, 0, 1);
    } else {
        // legacy 24MB path
        unsigned short* kbuf = (unsigned short*)(ws + 1024);
        unsigned short* vbuf = (unsigned short*)(ws + 1024 + (4u << 20));
        unsigned short* abuf = (unsigned short*)(ws + 1024 + (8u << 20));
        unsigned short* qbuf = (unsigned short*)d_out;
        const unsigned short* hdet = (const unsigned short*)hidden;
        gemm_bt<<<dim3(M_ROWS / 64, D_MODEL / 64), blk, 0, stream>>>(hidden, Wq, qbuf, D_MODEL, hdet, 1, 1, 0);
        gemm_bt<<<dim3(M_ROWS / 64, (NKVH * HEAD_DIM) / 64), blk, 0, stream>>>(hidden, Wk, kbuf, NKVH * HEAD_DIM, hdet, 1, 1, 0);
        gemm_bt<<<dim3(M_ROWS / 64, (NKVH * HEAD_DIM) / 64), blk, 0, stream>>>(hidden, Wv, vbuf, NKVH * HEAD_DIM, hdet, 1, 0, 0);
        attn_kernel<<<dim3(2 * NHEAD * (S_LEN / 64)), blk, 0, stream>>>(qbuf, kbuf, vbuf, abuf, 512);
        gemm_bt<<<dim3(M_ROWS / 64, D_MODEL / 64), blk, 0, stream>>>(abuf, Wo, d_out, D_MODEL, hdet, 0, 0, 1);
    }
}

// Round 12
// 389.810 us; speedup vs baseline: 2.8695x; 1.0843x over previous
//
#include <hip/hip_runtime.h>

// FlashAttentionWrapper: B=2, S=2048, D=2048, NH=32, HD=64, NKV=8, NREP=4,
// causal, RoPE theta=1e4. Input dtype (bf16/f32) self-detected per block.
// New-path workspace (64MB+1KB+512KB):
//   [1KB pad][kvbuf 4096x1024 8MB][abuf 4096x2048 16MB]
//   [hbuf 16MB][wqb 8MB][wkvb 4MB][wob 8MB][vtbuf 2x512x2048 4MB]
//   [ropetab 2048x32 float2 512KB]
// wqb+wkvb are CONTIGUOUS => one [3072,2048] QKV weight matrix (fused GEMM).
// Q-projection result lives in d_out (dead before O-proj overwrites it).
// Fallback path (ws too small): original direct-load kernels, 24MB+1KB.
//
// Round-5:  hand-written cvt_pk asm mis-packed (absmax 3.6) — no blind asm.
// Round-8:  forced launch_bounds occupancy => scratch spill (32x traffic).
// Round-10: 2-phase GEMM dbuf null (barrier drain hidden only by TLP).
// Round-11: __expf vs exp2f null — attn is latency-structural; parked at 138us.
// Round-12: GEMM BK=32 -> BK=64 (single 32KB LDS buffer, same occupancy):
//   halves the number of per-K-step barrier drains. 128-B LDS rows need the
//   G4 XOR swizzle byte^=((row&7)<<4), applied BOTH sides (rule #21): linear
//   gload_lds dest + inverse-swizzled GLOBAL source col + swizzled ds_read.

#define S_LEN 2048
#define D_MODEL 2048
#define NHEAD 32
#define HEAD_DIM 64
#define NKVH 8
#define M_ROWS 4096   // B*S
#define KVW (NKVH * HEAD_DIM)   // 512

typedef __attribute__((ext_vector_type(4))) float f32x4;
typedef __attribute__((ext_vector_type(8))) short bf16x8;

#define MFMA16(a, b, c) __builtin_amdgcn_mfma_f32_16x16x32_bf16((a), (b), (c), 0, 0, 0)

// async global->LDS, 16B per lane; LDS dest is wave-uniform base + lane*16
#define GLOAD_LDS16(g, l)                                                     \
    __builtin_amdgcn_global_load_lds(                                         \
        (const __attribute__((address_space(1))) void*)(g),                   \
        (__attribute__((address_space(3))) void*)(l), 16, 0, 0)

// f32 -> bf16 RNE via native cast (compiler emits the HW convert).
static __device__ __forceinline__ unsigned short f2bf(float f) {
    union { __bf16 b; unsigned short u; } v;
    v.b = (__bf16)f;
    return v.u;
}

// XCD-chunked swizzle of a 2D grid (requires gridDim.x*gridDim.y % 8 == 0).
static __device__ __forceinline__ void xcd_swz(int& bx, int& by) {
    const int gx = gridDim.x;
    const int nwg = gx * gridDim.y;
    int lin = blockIdx.y * gx + blockIdx.x;
    lin = (lin & 7) * (nwg >> 3) + (lin >> 3);
    bx = lin % gx;
    by = lin / gx;
}

// ---------------------------------------------------------------------------
// Per-block dtype self-detection: f32 data read as uint16 shows impossible
// bf16 exponents at even indices. Called uniformly by all 256 threads.
// ---------------------------------------------------------------------------
static __device__ bool detect_f32_block(const unsigned short* __restrict__ h) {
    __shared__ int dcnt;
    if (threadIdx.x == 0) dcnt = 0;
    __syncthreads();
    const unsigned short v = h[2 * (threadIdx.x & 255)];
    const int e = (v >> 7) & 0xFF;
    if (threadIdx.x < 256 && e >= 0x8D) atomicAdd(&dcnt, 1);
    __syncthreads();
    return dcnt >= 8;
}

static __device__ __forceinline__ bf16x8 load_frag(bool f32p, const void* p, size_t off) {
    if (f32p) {
        const float* fp = (const float*)p + off;
        f32x4 x = *reinterpret_cast<const f32x4*>(fp);
        f32x4 y = *reinterpret_cast<const f32x4*>(fp + 4);
        bf16x8 r;
        r[0] = (short)f2bf(x[0]); r[1] = (short)f2bf(x[1]);
        r[2] = (short)f2bf(x[2]); r[3] = (short)f2bf(x[3]);
        r[4] = (short)f2bf(y[0]); r[5] = (short)f2bf(y[1]);
        r[6] = (short)f2bf(y[2]); r[7] = (short)f2bf(y[3]);
        return r;
    }
    return *reinterpret_cast<const bf16x8*>((const unsigned short*)p + off);
}

// ---------------------------------------------------------------------------
// Fused one-time f32->bf16 conversion (or bf16 copy) of all 5 operands,
// plus the RoPE cos/sin table (tab[s*32+dd] = cos/sin of s*10000^(-dd/32)).
// ---------------------------------------------------------------------------
__global__ __launch_bounds__(256) void cvt_all(const void* __restrict__ h,
                                               const void* __restrict__ wq,
                                               const void* __restrict__ wk,
                                               const void* __restrict__ wv,
                                               const void* __restrict__ wo,
                                               unsigned short* __restrict__ hbuf,
                                               unsigned short* __restrict__ wqb,
                                               unsigned short* __restrict__ wkvb,
                                               unsigned short* __restrict__ wob,
                                               float2* __restrict__ ropetab) {
    const bool f32p = detect_f32_block((const unsigned short*)h);
    const int e0 = 1048576;            // hidden 4096x2048
    const int e1 = e0 + 524288;        // Wq 2048x2048
    const int e2 = e1 + 131072;        // Wk 512x2048
    const int e3 = e2 + 131072;        // Wv 512x2048
    const int e4 = e3 + 524288;        // Wo 2048x2048
    const int e5 = e4 + 8192;          // rope table 2048x32 (8 entries/unit)
    int i = blockIdx.x * 256 + threadIdx.x;
    const int stride = gridDim.x * 256;
    for (; i < e5; i += stride) {
        if (i >= e4) {
            const int base = (i - e4) * 8;
#pragma unroll
            for (int j = 0; j < 8; ++j) {
                const int idx = base + j;
                const int s = idx >> 5, dd = idx & 31;
                const float inv = exp2f(-(float)dd * 0.4152410118609203f);
                const float th = (float)s * inv;
                float sn, cs;
                sincosf(th, &sn, &cs);
                ropetab[idx] = make_float2(cs, sn);
            }
            continue;
        }
        const void* s;
        unsigned short* d;
        size_t off;
        if (i < e0)      { s = h;  d = hbuf; off = (size_t)i; }
        else if (i < e1) { s = wq; d = wqb;  off = (size_t)(i - e0); }
        else if (i < e2) { s = wk; d = wkvb; off = (size_t)(i - e1); }
        else if (i < e3) { s = wv; d = wkvb + (size_t)512 * 2048; off = (size_t)(i - e2); }
        else             { s = wo; d = wob;  off = (size_t)(i - e3); }
        bf16x8 v = load_frag(f32p, s, off * 8);
        *reinterpret_cast<bf16x8*>(d + off * 8) = v;
    }
}

// ---------------------------------------------------------------------------
// RoPE epilogue helpers.
// ---------------------------------------------------------------------------
static __device__ __forceinline__ void rope4_tab(const float2* __restrict__ tab,
                                                 const float (&vals)[4], float (&outv)[4],
                                                 int m, int l16) {
    const int s = m & (S_LEN - 1);
#pragma unroll
    for (int nt = 0; nt < 4; ++nt) {
        const int d = nt * 16 + l16;
        const float2 cs = tab[s * 32 + (d & 31)];
        const float part = vals[nt ^ 2];
        const float rot = (nt < 2) ? -part : part;  // d<32: -x2 ; d>=32: +x1
        outv[nt] = vals[nt] * cs.x + rot * cs.y;
    }
}

static __device__ __forceinline__ void rope4(const float (&vals)[4], float (&outv)[4],
                                             int m, int l16) {
    const float sf = (float)(m & (S_LEN - 1));
#pragma unroll
    for (int nt = 0; nt < 4; ++nt) {
        const int d = nt * 16 + l16;
        const float inv = exp2f(-(float)(d & 31) * 0.4152410118609203f);
        const float th = sf * inv;
        float sn, cs;
        sincosf(th, &sn, &cs);
        const float part = vals[nt ^ 2];
        const float rot = (nt < 2) ? -part : part;
        outv[nt] = vals[nt] * cs + rot * sn;
    }
}

// ---------------------------------------------------------------------------
// BK=64 GEMM core, single 32KB LDS buffer, 2 barriers per K-step (verified
// m97-family structure), 32 steps. LDS rows are 128B => XOR-swizzled layout:
//   LDS[row][col_bytes ^ ((row&7)<<4)] holds logical (row, col).
// Staging chunk c (= wave*4+i) covers rows 8c..8c+8; staging lane l's linear
// LDS slot (row 8c+(l>>3), byte (l&7)*16) is filled from the PRE-SWIZZLED
// global column ((l&7)*16) ^ ((l>>3)<<4)  [row&7 == l>>3 since 8c%8==0].
// Reads apply the same XOR => round-trips to logical data (rule #21).
// ---------------------------------------------------------------------------
#define GEMM_PTR_SETUP(ABASE, WBASE)                                          \
    const int l8r = lane >> 3;                                                \
    const int scol_sw = ((((lane & 7) * 16) ^ (l8r << 4)) >> 1);              \
    const unsigned short* ag[4];                                              \
    const unsigned short* wg[4];                                              \
    _Pragma("unroll")                                                         \
    for (int i = 0; i < 4; ++i) {                                             \
        const int c = wave * 4 + i;                                           \
        ag[i] = (ABASE) + (size_t)(m0 + c * 8 + l8r) * D_MODEL + scol_sw;     \
        wg[i] = (WBASE) + (size_t)(n0 + c * 8 + l8r) * D_MODEL + scol_sw;     \
    }

#define GEMM_MAINLOOP()                                                       \
    for (int k0 = 0; k0 < D_MODEL; k0 += 64) {                                \
        _Pragma("unroll")                                                     \
        for (int i_ = 0; i_ < 4; ++i_) {                                      \
            const int c_ = wave * 4 + i_;                                     \
            GLOAD_LDS16(ag[i_] + k0, &lds_a[c_ * 512]);                       \
            GLOAD_LDS16(wg[i_] + k0, &lds_b[c_ * 512]);                       \
        }                                                                     \
        __syncthreads();                                                      \
        _Pragma("unroll")                                                     \
        for (int kh = 0; kh < 2; ++kh) {                                      \
            bf16x8 af[4], bfm[4];                                             \
            _Pragma("unroll")                                                 \
            for (int t = 0; t < 4; ++t) {                                     \
                const int ra = wm * 64 + t * 16 + l16;                        \
                const int rb = wn * 64 + t * 16 + l16;                        \
                const int offb = ((kh * 64) | (quad * 16)) ^ ((l16 & 7) << 4);\
                af[t]  = *reinterpret_cast<const bf16x8*>(                    \
                    &lds_a[ra * 64 + (offb >> 1)]);                           \
                bfm[t] = *reinterpret_cast<const bf16x8*>(                    \
                    &lds_b[rb * 64 + (offb >> 1)]);                           \
            }                                                                 \
            _Pragma("unroll")                                                 \
            for (int mt = 0; mt < 4; ++mt)                                    \
                _Pragma("unroll")                                             \
                for (int nt = 0; nt < 4; ++nt)                                \
                    acc[mt][nt] = MFMA16(af[mt], bfm[nt], acc[mt][nt]);       \
        }                                                                     \
        __syncthreads();                                                      \
    }

// ---------------------------------------------------------------------------
// Fused QKV GEMM: A[4096,2048] @ Wqkv[3072,2048]^T, all bf16. 128x128 tile,
// BK=64 swizzled single-buffer staging, 4 waves 2x2, XCD swizzle. Epilogue
// routes each wave's head-aligned 64-col span: cols<2048 -> Q (RoPE);
// 2048..2559 -> K half of kvbuf (RoPE); >=2560 -> V half (no RoPE).
// ---------------------------------------------------------------------------
__global__ __launch_bounds__(256) void gemm_qkv_lds(const unsigned short* __restrict__ A,
                                                    const unsigned short* __restrict__ W,
                                                    unsigned short* __restrict__ Qo,
                                                    unsigned short* __restrict__ KVo,
                                                    const float2* __restrict__ ropetab) {
    __shared__ unsigned short lds_a[128 * 64];   // 16KB
    __shared__ unsigned short lds_b[128 * 64];   // 16KB

    const int wave = threadIdx.x >> 6;
    const int lane = threadIdx.x & 63;
    const int l16  = lane & 15;
    const int quad = lane >> 4;
    const int wm   = wave >> 1;
    const int wn   = wave & 1;

    int bx, by;
    xcd_swz(bx, by);
    const int m0 = bx * 128;
    const int n0 = by * 128;

    GEMM_PTR_SETUP(A, W);

    f32x4 acc[4][4];
#pragma unroll
    for (int i = 0; i < 4; ++i)
#pragma unroll
        for (int j = 0; j < 4; ++j) acc[i][j] = (f32x4){0.f, 0.f, 0.f, 0.f};

    GEMM_MAINLOOP();

    const int ncol0 = n0 + wn * 64;                 // wave-uniform, head-aligned
    const bool do_rope = (ncol0 < 2048 + KVW);      // Q and K regions
    unsigned short* dst;
    int cstride, c0;
    if (ncol0 < 2048) { dst = Qo;  cstride = 2048; c0 = ncol0; }
    else              { dst = KVo; cstride = 1024; c0 = ncol0 - 2048; }

#pragma unroll
    for (int mt = 0; mt < 4; ++mt) {
#pragma unroll
        for (int r = 0; r < 4; ++r) {
            const int m = m0 + wm * 64 + mt * 16 + quad * 4 + r;
            float vals[4];
#pragma unroll
            for (int nt = 0; nt < 4; ++nt) vals[nt] = acc[mt][nt][r];
            float outv[4];
            if (do_rope) {
                rope4_tab(ropetab, vals, outv, m, l16);
            } else {
#pragma unroll
                for (int nt = 0; nt < 4; ++nt) outv[nt] = vals[nt];
            }
            unsigned short* cp = dst + (size_t)m * cstride + c0;
#pragma unroll
            for (int nt = 0; nt < 4; ++nt) cp[nt * 16 + l16] = f2bf(outv[nt]);
        }
    }
}

// ---------------------------------------------------------------------------
// O-projection GEMM: C[M,N] = A[M,2048] @ W[N,2048]^T, bf16, BK=64 swizzled
// staging, XCD swizzle. finalout + f32 input -> f32 output (self-detect).
// ---------------------------------------------------------------------------
__global__ __launch_bounds__(256) void gemm_bt_lds(const unsigned short* __restrict__ A,
                                                   const unsigned short* __restrict__ W,
                                                   void* __restrict__ Cp, int N,
                                                   const unsigned short* __restrict__ hdet,
                                                   int rope, int finalout) {
    __shared__ unsigned short lds_a[128 * 64];
    __shared__ unsigned short lds_b[128 * 64];

    bool of32 = false;
    if (finalout) of32 = detect_f32_block(hdet);

    const int wave = threadIdx.x >> 6;
    const int lane = threadIdx.x & 63;
    const int l16  = lane & 15;
    const int quad = lane >> 4;
    const int wm   = wave >> 1;
    const int wn   = wave & 1;

    int bx, by;
    xcd_swz(bx, by);
    const int m0 = bx * 128;
    const int n0 = by * 128;

    GEMM_PTR_SETUP(A, W);

    f32x4 acc[4][4];
#pragma unroll
    for (int i = 0; i < 4; ++i)
#pragma unroll
        for (int j = 0; j < 4; ++j) acc[i][j] = (f32x4){0.f, 0.f, 0.f, 0.f};

    GEMM_MAINLOOP();

    const bool do_rope = (rope != 0);
    const int ncol0 = n0 + wn * 64;

#pragma unroll
    for (int mt = 0; mt < 4; ++mt) {
#pragma unroll
        for (int r = 0; r < 4; ++r) {
            const int m = m0 + wm * 64 + mt * 16 + quad * 4 + r;
            float vals[4];
#pragma unroll
            for (int nt = 0; nt < 4; ++nt) vals[nt] = acc[mt][nt][r];
            float outv[4];
            if (do_rope) {
                rope4(vals, outv, m, l16);
            } else {
#pragma unroll
                for (int nt = 0; nt < 4; ++nt) outv[nt] = vals[nt];
            }
            const size_t crow = (size_t)m * N + ncol0;
            if (of32) {
                float* cp = (float*)Cp + crow;
#pragma unroll
                for (int nt = 0; nt < 4; ++nt) cp[nt * 16 + l16] = outv[nt];
            } else {
                unsigned short* cp = (unsigned short*)Cp + crow;
#pragma unroll
                for (int nt = 0; nt < 4; ++nt) cp[nt * 16 + l16] = f2bf(outv[nt]);
            }
        }
    }
}

// ---------------------------------------------------------------------------
// V transpose: Vsrc = kvbuf V-half [B*S rows, stride 1024] cols 0..511
//   -> Vt[b][c][s] ([B][512][S]).  64x64 LDS tiles, fully coalesced.
// ---------------------------------------------------------------------------
__global__ __launch_bounds__(256) void transpose_v(const unsigned short* __restrict__ Vsrc,
                                                   unsigned short* __restrict__ Vt) {
    __shared__ unsigned short t[64][72];
    const int bid = blockIdx.x;
    const int ct = bid & 7;
    const int st = (bid >> 3) & 31;
    const int b  = bid >> 8;
    const unsigned short* src = Vsrc + ((size_t)b * S_LEN + st * 64) * 1024 + ct * 64;
    unsigned short* dst = Vt + ((size_t)b * KVW + ct * 64) * S_LEN + st * 64;
    const int r0 = threadIdx.x >> 3;
    const int c0 = (threadIdx.x & 7) * 8;
#pragma unroll
    for (int h = 0; h < 2; ++h) {
        bf16x8 v = *reinterpret_cast<const bf16x8*>(src + (size_t)(r0 + h * 32) * 1024 + c0);
        *reinterpret_cast<bf16x8*>(&t[r0 + h * 32][c0]) = v;
    }
    __syncthreads();
#pragma unroll
    for (int h = 0; h < 2; ++h) {
        const int cr = r0 + h * 32;
        bf16x8 v;
#pragma unroll
        for (int j = 0; j < 8; ++j) v[j] = (short)t[c0 + j][cr];
        *reinterpret_cast<bf16x8*>(dst + (size_t)cr * S_LEN + c0) = v;
    }
}

// ---------------------------------------------------------------------------
// Flash attention v8 (round-11 verified, 138us): single-buffered K, vf-early,
// row-sum via MFMA, deferred max (THR=8ln2), natural-log softmax w/ __expf.
// ---------------------------------------------------------------------------
struct AttnCtx {
    const unsigned short* qbase;
    const unsigned short* kbase;
    const unsigned short* vtbase;
    unsigned short* obase;
    int kvs;
    int l16, quad;
    unsigned short (*lpw)[72];   // [32][72] per-wave slice
};

#define SM_SCALE 0.125f               // 1/sqrt(HD)
#define SM_THR_E 5.545177444479562f   // 8 * ln2

static __device__ __forceinline__ void attn_qtile(const AttnCtx& cx, int q0w) {
    const int l16 = cx.l16, quad = cx.quad;
    const int kvs = cx.kvs;

    bf16x8 ones;
#pragma unroll
    for (int j = 0; j < 8; ++j) ones[j] = (short)0x3F80;   // bf16 1.0

    bf16x8 aq[2][2];
#pragma unroll
    for (int m = 0; m < 2; ++m)
#pragma unroll
        for (int kh = 0; kh < 2; ++kh)
            aq[m][kh] = *reinterpret_cast<const bf16x8*>(
                cx.qbase + (size_t)(q0w + m * 16 + l16) * D_MODEL + kh * 32 + quad * 8);

    f32x4 o[2][4];
    f32x4 c_l[2];     // row-sum accumulator (l = P @ ones)
#pragma unroll
    for (int m = 0; m < 2; ++m) {
#pragma unroll
        for (int i = 0; i < 4; ++i) o[m][i] = (f32x4){0.f, 0.f, 0.f, 0.f};
        c_l[m] = (f32x4){0.f, 0.f, 0.f, 0.f};
    }
    float m2[2][4];   // running max, natural-log domain
#pragma unroll
    for (int m = 0; m < 2; ++m)
#pragma unroll
        for (int r = 0; r < 4; ++r) m2[m][r] = 0.f;

    const int kv_hi = q0w + 32;   // per-wave causal bound

    for (int k0 = 0; k0 < kv_hi; k0 += 64) {
        // ---- K fragments (single buffer; regs freed after QK^T) ----
        bf16x8 kf[8];
#pragma unroll
        for (int t = 0; t < 4; ++t) {
            const unsigned short* krow = cx.kbase + (size_t)(k0 + t * 16 + l16) * kvs;
            kf[2 * t]     = *reinterpret_cast<const bf16x8*>(krow + quad * 8);
            kf[2 * t + 1] = *reinterpret_cast<const bf16x8*>(krow + 32 + quad * 8);
        }

        f32x4 sc[2][4];
        __builtin_amdgcn_s_setprio(1);
#pragma unroll
        for (int t = 0; t < 4; ++t) {
#pragma unroll
            for (int m = 0; m < 2; ++m) {
                f32x4 c = (f32x4){0.f, 0.f, 0.f, 0.f};
                c = MFMA16(aq[m][0], kf[2 * t], c);
                c = MFMA16(aq[m][1], kf[2 * t + 1], c);
                sc[m][t] = c;
            }
        }
        __builtin_amdgcn_s_setprio(0);

        // ---- V fragments issued early (cover latency under softmax) ----
        bf16x8 vf[8];
#pragma unroll
        for (int nt = 0; nt < 4; ++nt) {
            const unsigned short* vrow =
                cx.vtbase + (size_t)(nt * 16 + l16) * S_LEN + k0 + quad * 8;
            vf[2 * nt]     = *reinterpret_cast<const bf16x8*>(vrow);
            vf[2 * nt + 1] = *reinterpret_cast<const bf16x8*>(vrow + 32);
        }

        const bool full = (k0 + 63 <= q0w);
        float pm[2][4];
        float dif = -3.0e38f;
#pragma unroll
        for (int m = 0; m < 2; ++m) {
#pragma unroll
            for (int r = 0; r < 4; ++r) {
                const int qi = q0w + m * 16 + quad * 4 + r;
                float s[4];
#pragma unroll
                for (int t = 0; t < 4; ++t) {
                    s[t] = sc[m][t][r] * SM_SCALE;
                    if (!full && (k0 + t * 16 + l16 > qi)) s[t] = -1.0e30f;
                    sc[m][t][r] = s[t];
                }
                const float p = fmaxf(fmaxf(s[0], s[1]), fmaxf(s[2], s[3]));
                pm[m][r] = p;
                dif = fmaxf(dif, p - m2[m][r]);
            }
        }
        if (__any(dif > SM_THR_E)) {
#pragma unroll
            for (int m = 0; m < 2; ++m) {
#pragma unroll
                for (int r = 0; r < 4; ++r) {
                    float mt = pm[m][r];
#pragma unroll
                    for (int off = 1; off < 16; off <<= 1)
                        mt = fmaxf(mt, __shfl_xor(mt, off, 64));
                    const float mn = fmaxf(m2[m][r], mt);
                    const float al = __expf(m2[m][r] - mn);
                    m2[m][r] = mn;
#pragma unroll
                    for (int nt = 0; nt < 4; ++nt) o[m][nt][r] *= al;
                    c_l[m][r] *= al;
                }
            }
        }
        // pass 2: p = exp(s - m2), write P tile
#pragma unroll
        for (int m = 0; m < 2; ++m) {
#pragma unroll
            for (int r = 0; r < 4; ++r) {
                const float mb = m2[m][r];
#pragma unroll
                for (int t = 0; t < 4; ++t) {
                    const float pv = __expf(sc[m][t][r] - mb);
                    cx.lpw[m * 16 + quad * 4 + r][t * 16 + l16] = f2bf(pv);
                }
            }
        }
        asm volatile("" ::: "memory");
        bf16x8 ap[2][2];
#pragma unroll
        for (int m = 0; m < 2; ++m)
#pragma unroll
            for (int kh = 0; kh < 2; ++kh)
                ap[m][kh] = *reinterpret_cast<const bf16x8*>(
                    &cx.lpw[m * 16 + l16][kh * 32 + quad * 8]);
        __builtin_amdgcn_s_setprio(1);
#pragma unroll
        for (int nt = 0; nt < 4; ++nt)
#pragma unroll
            for (int m = 0; m < 2; ++m) {
                o[m][nt] = MFMA16(ap[m][0], vf[2 * nt], o[m][nt]);
                o[m][nt] = MFMA16(ap[m][1], vf[2 * nt + 1], o[m][nt]);
            }
#pragma unroll
        for (int m = 0; m < 2; ++m) {
            c_l[m] = MFMA16(ap[m][0], ones, c_l[m]);
            c_l[m] = MFMA16(ap[m][1], ones, c_l[m]);
        }
        __builtin_amdgcn_s_setprio(0);
    }

#pragma unroll
    for (int m = 0; m < 2; ++m)
#pragma unroll
        for (int r = 0; r < 4; ++r) {
            const float inv_l = 1.0f / c_l[m][r];
            unsigned short* orow = cx.obase + (size_t)(q0w + m * 16 + quad * 4 + r) * D_MODEL;
#pragma unroll
            for (int nt = 0; nt < 4; ++nt)
                orow[nt * 16 + l16] = f2bf(o[m][nt][r] * inv_l);
        }
}

__global__ __launch_bounds__(256) void attn_kernel8(const unsigned short* __restrict__ Q,
                                                    const unsigned short* __restrict__ Kb,
                                                    const unsigned short* __restrict__ Vt,
                                                    unsigned short* __restrict__ O, int kvs) {
    __shared__ unsigned short lp[4][32][72];   // per-wave P (32 q x 64 k), padded

    const int wave = threadIdx.x >> 6;
    const int lane = threadIdx.x & 63;

    const int bid  = blockIdx.x;
    const int qt   = 15 - (bid >> 6);
    const int bh   = bid & 63;
    const int h    = bh & (NHEAD - 1);
    const int b    = bh >> 5;
    const int kvh  = h >> 2;

    AttnCtx cx;
    cx.qbase  = Q + (size_t)b * S_LEN * D_MODEL + h * HEAD_DIM;
    cx.kbase  = Kb + (size_t)b * S_LEN * kvs + kvh * HEAD_DIM;
    cx.vtbase = Vt + ((size_t)b * KVW + kvh * HEAD_DIM) * S_LEN;
    cx.obase  = O + (size_t)b * S_LEN * D_MODEL + h * HEAD_DIM;
    cx.kvs    = kvs;
    cx.l16    = lane & 15;
    cx.quad   = lane >> 4;
    cx.lpw    = lp[wave];

    attn_qtile(cx, qt * 128 + wave * 32);
}

// ---------------------------------------------------------------------------
// Legacy direct-load GEMM + attention (fallback path only).
// ---------------------------------------------------------------------------
__global__ __launch_bounds__(256) void gemm_bt(const void* __restrict__ Ap,
                                               const void* __restrict__ Wp,
                                               void* __restrict__ Cp, int N,
                                               const unsigned short* __restrict__ hdet,
                                               int a_input, int rope, int finalout) {
    const bool isf32 = detect_f32_block(hdet);
    const bool af32 = isf32 && (a_input != 0);
    const bool wf32 = isf32;
    const bool of32 = isf32 && (finalout != 0);

    const int wave = threadIdx.x >> 6;
    const int lane = threadIdx.x & 63;
    const int l16  = lane & 15;
    const int quad = lane >> 4;
    const int m0 = blockIdx.x * 64 + wave * 16;
    const int n0 = blockIdx.y * 64;

    f32x4 acc[4];
#pragma unroll
    for (int i = 0; i < 4; ++i) acc[i] = (f32x4){0.f, 0.f, 0.f, 0.f};

    const size_t aoff = (size_t)(m0 + l16) * D_MODEL + quad * 8;
    size_t woff[4];
#pragma unroll
    for (int nt = 0; nt < 4; ++nt)
        woff[nt] = (size_t)(n0 + nt * 16 + l16) * D_MODEL + quad * 8;

    for (int k0 = 0; k0 < D_MODEL; k0 += 32) {
        bf16x8 a = load_frag(af32, Ap, aoff + k0);
#pragma unroll
        for (int nt = 0; nt < 4; ++nt) {
            bf16x8 b = load_frag(wf32, Wp, woff[nt] + k0);
            acc[nt] = MFMA16(a, b, acc[nt]);
        }
    }

#pragma unroll
    for (int r = 0; r < 4; ++r) {
        const int m = m0 + quad * 4 + r;
        float vals[4];
#pragma unroll
        for (int nt = 0; nt < 4; ++nt) vals[nt] = acc[nt][r];
        float outv[4];
        if (rope) {
            rope4(vals, outv, m, l16);
        } else {
#pragma unroll
            for (int nt = 0; nt < 4; ++nt) outv[nt] = vals[nt];
        }
        const size_t crow = (size_t)m * N + n0;
        if (of32) {
            float* cp = (float*)Cp + crow;
#pragma unroll
            for (int nt = 0; nt < 4; ++nt) cp[nt * 16 + l16] = outv[nt];
        } else {
            unsigned short* cp = (unsigned short*)Cp + crow;
#pragma unroll
            for (int nt = 0; nt < 4; ++nt) cp[nt * 16 + l16] = f2bf(outv[nt]);
        }
    }
}

__global__ __launch_bounds__(256) void attn_kernel(const unsigned short* __restrict__ Q,
                                                   const unsigned short* __restrict__ Kb,
                                                   const unsigned short* __restrict__ Vb,
                                                   unsigned short* __restrict__ O, int kvs) {
    __shared__ unsigned short lp[4][16][32];

    const int wave = threadIdx.x >> 6;
    const int lane = threadIdx.x & 63;
    const int l16  = lane & 15;
    const int quad = lane >> 4;

    const int bid = blockIdx.x;
    const int qb  = bid & 31;
    const int h   = (bid >> 5) & 31;
    const int b   = bid >> 10;
    const int kvh = h >> 2;
    const int q0  = qb * 64 + wave * 16;

    const unsigned short* qbase = Q + (size_t)b * S_LEN * D_MODEL + h * HEAD_DIM;
    const unsigned short* kbase = Kb + (size_t)b * S_LEN * kvs + kvh * HEAD_DIM;
    const unsigned short* vbase = Vb + (size_t)b * S_LEN * kvs + kvh * HEAD_DIM;

    bf16x8 aq0 = *reinterpret_cast<const bf16x8*>(qbase + (size_t)(q0 + l16) * D_MODEL + quad * 8);
    bf16x8 aq1 = *reinterpret_cast<const bf16x8*>(qbase + (size_t)(q0 + l16) * D_MODEL + 32 + quad * 8);

    f32x4 o[4];
#pragma unroll
    for (int i = 0; i < 4; ++i) o[i] = (f32x4){0.f, 0.f, 0.f, 0.f};
    float mrow[4], lrow[4];
#pragma unroll
    for (int r = 0; r < 4; ++r) { mrow[r] = -3.0e38f; lrow[r] = 0.f; }

    const int kv_hi = qb * 64 + 64;
    for (int k0 = 0; k0 < kv_hi; k0 += 32) {
        f32x4 sc[2];
#pragma unroll
        for (int t = 0; t < 2; ++t) {
            const unsigned short* krow = kbase + (size_t)(k0 + t * 16 + l16) * kvs;
            bf16x8 b0 = *reinterpret_cast<const bf16x8*>(krow + quad * 8);
            bf16x8 b1 = *reinterpret_cast<const bf16x8*>(krow + 32 + quad * 8);
            f32x4 c = (f32x4){0.f, 0.f, 0.f, 0.f};
            c = MFMA16(aq0, b0, c);
            c = MFMA16(aq1, b1, c);
            sc[t] = c;
        }

        float alpha[4], p0v[4], p1v[4];
#pragma unroll
        for (int r = 0; r < 4; ++r) {
            const int qi = q0 + quad * 4 + r;
            float s0 = sc[0][r] * 0.125f;
            float s1 = sc[1][r] * 0.125f;
            if (k0 + l16 > qi)       s0 = -1.0e30f;
            if (k0 + 16 + l16 > qi)  s1 = -1.0e30f;
            float mt = fmaxf(s0, s1);
#pragma unroll
            for (int off = 1; off < 16; off <<= 1) mt = fmaxf(mt, __shfl_xor(mt, off, 64));
            const float mn = fmaxf(mrow[r], mt);
            const float al = __expf(mrow[r] - mn);
            const float p0 = __expf(s0 - mn);
            const float p1 = __expf(s1 - mn);
            float rs = p0 + p1;
#pragma unroll
            for (int off = 1; off < 16; off <<= 1) rs += __shfl_xor(rs, off, 64);
            lrow[r] = lrow[r] * al + rs;
            mrow[r] = mn;
            alpha[r] = al;
            p0v[r] = p0; p1v[r] = p1;
        }
#pragma unroll
        for (int nt = 0; nt < 4; ++nt)
#pragma unroll
            for (int r = 0; r < 4; ++r) o[nt][r] *= alpha[r];

        __syncthreads();
#pragma unroll
        for (int r = 0; r < 4; ++r) {
            lp[wave][quad * 4 + r][l16]      = f2bf(p0v[r]);
            lp[wave][quad * 4 + r][16 + l16] = f2bf(p1v[r]);
        }
        __syncthreads();
        bf16x8 ap = *reinterpret_cast<const bf16x8*>(&lp[wave][l16][quad * 8]);

#pragma unroll
        for (int nt = 0; nt < 4; ++nt) {
            const unsigned short* vcol = vbase + nt * 16 + l16 + (size_t)(k0 + quad * 8) * kvs;
            bf16x8 bv;
#pragma unroll
            for (int j = 0; j < 8; ++j) bv[j] = (short)vcol[(size_t)j * kvs];
            o[nt] = MFMA16(ap, bv, o[nt]);
        }
    }

    unsigned short* obase = O + (size_t)b * S_LEN * D_MODEL + h * HEAD_DIM;
#pragma unroll
    for (int r = 0; r < 4; ++r) {
        const float inv_l = 1.0f / lrow[r];
        unsigned short* orow = obase + (size_t)(q0 + quad * 4 + r) * D_MODEL;
#pragma unroll
        for (int nt = 0; nt < 4; ++nt)
            orow[nt * 16 + l16] = f2bf(o[nt][r] * inv_l);
    }
}

extern "C" void kernel_launch(void* const* d_in, const int* in_sizes, int n_in,
                              void* d_out, int out_size, void* d_ws, size_t ws_size,
                              hipStream_t stream) {
    const void* hidden = d_in[0];
    const void* Wq = d_in[1];
    const void* Wk = d_in[2];
    const void* Wv = d_in[3];
    const void* Wo = d_in[4];
    // d_in[5] = attention_mask: pure causal -1e9 -> implemented directly.

    char* ws = (char*)d_ws;
    dim3 blk(256);

    // kv 8MB + abuf 16MB + hbuf 16MB + wq 8MB + wkv 4MB + wo 8MB + vt 4MB + tab 512KB
    const size_t NEED = 1024 + ((size_t)64 << 20) + (512u << 10);
    if (ws_size >= NEED) {
        unsigned short* kvbuf = (unsigned short*)(ws + 1024);      // [4096,1024]: K cols 0-511, V cols 512-1023
        unsigned short* abuf  = kvbuf + (size_t)4096 * 1024;       // [4096,2048]
        unsigned short* hbuf  = abuf + (size_t)4096 * 2048;        // hidden bf16
        unsigned short* wqb   = hbuf + (size_t)4096 * 2048;        // [2048,2048]  } contiguous =
        unsigned short* wkvb  = wqb + (size_t)2048 * 2048;         // [1024,2048]  } Wqkv [3072,2048]
        unsigned short* wob   = wkvb + (size_t)1024 * 2048;        // [2048,2048]
        unsigned short* vtbuf = wob + (size_t)2048 * 2048;         // [2,512,2048] V^T
        float2* ropetab       = (float2*)(vtbuf + (size_t)2 * 512 * 2048);  // [2048][32]
        unsigned short* qbuf  = (unsigned short*)d_out;            // Q bf16 lives in d_out

        cvt_all<<<dim3(2048), blk, 0, stream>>>(hidden, Wq, Wk, Wv, Wo,
                                                hbuf, wqb, wkvb, wob, ropetab);

        gemm_qkv_lds<<<dim3(32, 24), blk, 0, stream>>>(hbuf, wqb, qbuf, kvbuf, ropetab);
        transpose_v<<<dim3(512), blk, 0, stream>>>(kvbuf + 512, vtbuf);
        attn_kernel8<<<dim3(2 * NHEAD * (S_LEN / 128)), blk, 0, stream>>>(qbuf, kvbuf, vtbuf, abuf, 1024);
        gemm_bt_lds<<<dim3(32, 16), blk, 0, stream>>>(abuf, wob, d_out, 2048,
                                                      (const unsigned short*)hidden, 0, 1);
    } else {
        // legacy 24MB path
        unsigned short* kbuf = (unsigned short*)(ws + 1024);
        unsigned short* vbuf = (unsigned short*)(ws + 1024 + (4u << 20));
        unsigned short* abuf = (unsigned short*)(ws + 1024 + (8u << 20));
        unsigned short* qbuf = (unsigned short*)d_out;
        const unsigned short* hdet = (const unsigned short*)hidden;
        gemm_bt<<<dim3(M_ROWS / 64, D_MODEL / 64), blk, 0, stream>>>(hidden, Wq, qbuf, D_MODEL, hdet, 1, 1, 0);
        gemm_bt<<<dim3(M_ROWS / 64, (NKVH * HEAD_DIM) / 64), blk, 0, stream>>>(hidden, Wk, kbuf, NKVH * HEAD_DIM, hdet, 1, 1, 0);
        gemm_bt<<<dim3(M_ROWS / 64, (NKVH * HEAD_DIM) / 64), blk, 0, stream>>>(hidden, Wv, vbuf, NKVH * HEAD_DIM, hdet, 1, 0, 0);
        attn_kernel<<<dim3(2 * NHEAD * (S_LEN / 64)), blk, 0, stream>>>(qbuf, kbuf, vbuf, abuf, 512);
        gemm_bt<<<dim3(M_ROWS / 64, D_MODEL / 64), blk, 0, stream>>>(abuf, Wo, d_out, D_MODEL, hdet, 0, 0, 1);
    }
}